// Round 1
// baseline (4942.363 us; speedup 1.0000x reference)
//
#include <hip/hip_runtime.h>
#include <hip/hip_bf16.h>
#include <math.h>

using bf16 = __hip_bfloat16;
typedef __attribute__((ext_vector_type(8))) short s8v;
typedef __attribute__((ext_vector_type(4))) float f32x4;

#define D_MODEL 1024
#define NB 8
#define SEQ 1024
#define NHEAD 16
#define HD 64
#define MOE_H 2048
#define TOKENS (NB*SEQ)

// ---------------- fp32 -> bf16 convert ----------------
__global__ void f2b_k(const float* __restrict__ in, bf16* __restrict__ out, int n) {
    int i = blockIdx.x * blockDim.x + threadIdx.x;
    int stride = gridDim.x * blockDim.x;
    for (; i < n; i += stride) out[i] = __float2bfloat16(in[i]);
}

// ---------------- decomposition: trend + seasonal ----------------
__global__ __launch_bounds__(256) void decomp_k(
    const float* __restrict__ x, const float* __restrict__ alpha,
    const float* __restrict__ dw7, const float* __restrict__ dw25,
    const float* __restrict__ dw49, float* __restrict__ Tr, float* __restrict__ S)
{
    int n = blockIdx.x, b = blockIdx.y, t = threadIdx.x;
    float a0 = alpha[0], a1 = alpha[1], a2 = alpha[2];
    float mx = fmaxf(a0, fmaxf(a1, a2));
    float e0 = __expf(a0 - mx), e1 = __expf(a1 - mx), e2 = __expf(a2 - mx);
    float inv = 1.0f / (e0 + e1 + e2);
    float w7 = e0 * inv, w25 = e1 * inv, w49 = e2 * inv;
    for (int d = t; d < D_MODEL; d += 256) {
        float s7 = 0.f, s25 = 0.f, s49 = 0.f;
        for (int j = 0; j < 49; j++) {
            int i = n + j - 24;               // reflect padding (edge excluded)
            if (i < 0) i = -i;
            if (i > SEQ - 1) i = 2 * (SEQ - 1) - i;
            float xv = x[((size_t)(b * SEQ + i)) * D_MODEL + d];
            s49 += xv * dw49[d * 49 + j];
            if (j >= 12 && j < 37) s25 += xv * dw25[d * 25 + j - 12];
            if (j >= 21 && j < 28) s7  += xv * dw7 [d * 7  + j - 21];
        }
        float tr = w7 * s7 + w25 * s25 + w49 * s49;
        size_t idx = ((size_t)(b * SEQ + n)) * D_MODEL + d;
        Tr[idx] = tr;
        S[idx] = x[idx] - tr;
    }
}

// ---------------- LayerNorm (fp32 in, bf16 out, optional fp32 out) ----------------
__global__ __launch_bounds__(256) void ln_k(
    const float* __restrict__ x, const float* __restrict__ g, const float* __restrict__ b,
    bf16* __restrict__ ob, float* __restrict__ of)
{
    int row = blockIdx.x, t = threadIdx.x;
    const float* xr = x + (size_t)row * D_MODEL;
    float s = 0.f, s2 = 0.f;
    for (int d = t; d < D_MODEL; d += 256) { float v = xr[d]; s += v; s2 += v * v; }
    #pragma unroll
    for (int o = 32; o > 0; o >>= 1) { s += __shfl_down(s, o); s2 += __shfl_down(s2, o); }
    __shared__ float sh[8];
    int wid = t >> 6, lane = t & 63;
    if (lane == 0) { sh[wid] = s; sh[4 + wid] = s2; }
    __syncthreads();
    if (t == 0) {
        float ts = sh[0] + sh[1] + sh[2] + sh[3];
        float t2 = sh[4] + sh[5] + sh[6] + sh[7];
        float m = ts / D_MODEL;
        float var = t2 / D_MODEL - m * m;
        sh[0] = m; sh[1] = rsqrtf(var + 1e-5f);
    }
    __syncthreads();
    float m = sh[0], rs = sh[1];
    for (int d = t; d < D_MODEL; d += 256) {
        float v = (xr[d] - m) * rs * g[d] + b[d];
        ob[(size_t)row * D_MODEL + d] = __float2bfloat16(v);
        if (of) of[(size_t)row * D_MODEL + d] = v;
    }
}

// ---------------- bf16 MFMA GEMM: C[M,O] = A[M,K] @ B[O,K]^T (+bias)(+act) ----------------
// OMODE 0: fp32 out (+optional residual), 1: bf16 out, 2: fp32 accumulate += rowscale*(v)
template<int ACT, int OMODE>
__global__ __launch_bounds__(256) void gemm_nt(
    const bf16* __restrict__ A, const bf16* __restrict__ B,
    const float* __restrict__ bias, const float* resid,
    const float* __restrict__ rowscale, int rs_stride,
    void* C, int M, int K, int O)
{
    __shared__ bf16 As[128][72];
    __shared__ bf16 Bs[128][72];
    const int t = threadIdx.x;
    const int bm = blockIdx.x, bn = blockIdx.y;
    const int lane = t & 63, wid = t >> 6;
    const int wm = wid >> 1, wn = wid & 1;
    f32x4 acc[4][4] = {};
    const int lr = t >> 3;          // 0..31 (staging row within pass)
    const int lc = (t & 7) * 8;     // 0,8,...,56 (staging col)
    const size_t abase = (size_t)(bm * 128) * K;
    const size_t bbase = (size_t)(bn * 128) * K;
    for (int k0 = 0; k0 < K; k0 += 64) {
        #pragma unroll
        for (int p = 0; p < 4; p++) {
            int r = p * 32 + lr;
            *(s8v*)&As[r][lc] = *(const s8v*)&A[abase + (size_t)r * K + k0 + lc];
            *(s8v*)&Bs[r][lc] = *(const s8v*)&B[bbase + (size_t)r * K + k0 + lc];
        }
        __syncthreads();
        const int fr = lane & 15, fq = (lane >> 4) * 8;
        #pragma unroll
        for (int kk = 0; kk < 64; kk += 32) {
            s8v af[4], bfr[4];
            #pragma unroll
            for (int i = 0; i < 4; i++) {
                af[i]  = *(const s8v*)&As[wm * 64 + i * 16 + fr][kk + fq];
                bfr[i] = *(const s8v*)&Bs[wn * 64 + i * 16 + fr][kk + fq];
            }
            #pragma unroll
            for (int i = 0; i < 4; i++)
                #pragma unroll
                for (int j = 0; j < 4; j++)
                    acc[i][j] = __builtin_amdgcn_mfma_f32_16x16x32_bf16(af[i], bfr[j], acc[i][j], 0, 0, 0);
        }
        __syncthreads();
    }
    const int cr = lane & 15, quad = lane >> 4;
    #pragma unroll
    for (int i = 0; i < 4; i++) {
        #pragma unroll
        for (int j = 0; j < 4; j++) {
            #pragma unroll
            for (int r = 0; r < 4; r++) {
                int row = bm * 128 + wm * 64 + i * 16 + quad * 4 + r;
                int col = bn * 128 + wn * 64 + j * 16 + cr;
                float v = acc[i][j][r];
                if (bias) v += bias[col];
                if (ACT == 1) v = 0.5f * v * (1.0f + erff(v * 0.70710678118f));
                size_t idx = (size_t)row * O + col;
                if (OMODE == 0) {
                    float rv = resid ? resid[idx] : 0.0f;
                    ((float*)C)[idx] = rv + v;
                } else if (OMODE == 1) {
                    ((bf16*)C)[idx] = __float2bfloat16(v);
                } else {
                    ((float*)C)[idx] += rowscale[(size_t)row * rs_stride] * v;
                }
            }
        }
    }
}

// ---------------- flash attention with ALiBi, fixed-shift softmax ----------------
__global__ __launch_bounds__(256) void attn_k(
    const bf16* __restrict__ Q, const bf16* __restrict__ K,
    const bf16* __restrict__ V, bf16* __restrict__ Y)
{
    __shared__ float Ks[64][68];
    __shared__ float Vs[64][68];
    int b = blockIdx.z, h = blockIdx.y;
    int qrow = blockIdx.x * 256 + threadIdx.x;
    float slope = exp2f(-0.5f * (float)(h + 1));
    float q[HD], o[HD];
    float l = 0.f;
    const bf16* qp = Q + ((size_t)(b * SEQ + qrow)) * D_MODEL + h * HD;
    #pragma unroll
    for (int d = 0; d < HD; d++) { q[d] = __bfloat162float(qp[d]); o[d] = 0.f; }
    for (int k0 = 0; k0 < SEQ; k0 += 64) {
        __syncthreads();
        for (int i = threadIdx.x; i < 64 * 64; i += 256) {
            int r = i >> 6, c = i & 63;
            size_t gk = ((size_t)(b * SEQ + k0 + r)) * D_MODEL + h * HD + c;
            Ks[r][c] = __bfloat162float(K[gk]);
            Vs[r][c] = __bfloat162float(V[gk]);
        }
        __syncthreads();
        for (int kk = 0; kk < 64; kk++) {
            float s = 0.f;
            const float4* kr = (const float4*)&Ks[kk][0];
            #pragma unroll
            for (int d4 = 0; d4 < 16; d4++) {
                float4 kv = kr[d4];
                s = fmaf(q[4 * d4 + 0], kv.x, s);
                s = fmaf(q[4 * d4 + 1], kv.y, s);
                s = fmaf(q[4 * d4 + 2], kv.z, s);
                s = fmaf(q[4 * d4 + 3], kv.w, s);
            }
            int kg = k0 + kk;
            float dist = (kg > qrow) ? (float)(kg - qrow) : 0.0f;
            float p = __expf(s * 0.125f - slope * dist - 8.0f);
            l += p;
            const float4* vr = (const float4*)&Vs[kk][0];
            #pragma unroll
            for (int d4 = 0; d4 < 16; d4++) {
                float4 vv = vr[d4];
                o[4 * d4 + 0] = fmaf(p, vv.x, o[4 * d4 + 0]);
                o[4 * d4 + 1] = fmaf(p, vv.y, o[4 * d4 + 1]);
                o[4 * d4 + 2] = fmaf(p, vv.z, o[4 * d4 + 2]);
                o[4 * d4 + 3] = fmaf(p, vv.w, o[4 * d4 + 3]);
            }
        }
    }
    float invl = 1.0f / l;
    bf16* yp = Y + ((size_t)(b * SEQ + qrow)) * D_MODEL + h * HD;
    #pragma unroll
    for (int d = 0; d < HD; d++) yp[d] = __float2bfloat16(o[d] * invl);
}

// ---------------- router: fp32 gates, top-2 weights, aux accumulators ----------------
__global__ __launch_bounds__(64) void router_k(
    const float* __restrict__ xf, const float* __restrict__ rw,
    float* __restrict__ wts, float* __restrict__ auxb)
{
    int tk = blockIdx.x, lane = threadIdx.x;
    const float* xr = xf + (size_t)tk * D_MODEL;
    float p0 = 0, p1 = 0, p2 = 0, p3 = 0;
    for (int d = lane; d < D_MODEL; d += 64) {
        float v = xr[d];
        p0 += v * rw[d];
        p1 += v * rw[D_MODEL + d];
        p2 += v * rw[2 * D_MODEL + d];
        p3 += v * rw[3 * D_MODEL + d];
    }
    #pragma unroll
    for (int o = 32; o > 0; o >>= 1) {
        p0 += __shfl_down(p0, o); p1 += __shfl_down(p1, o);
        p2 += __shfl_down(p2, o); p3 += __shfl_down(p3, o);
    }
    if (lane == 0) {
        float g[4] = { p0, p1, p2, p3 };
        float mx = fmaxf(fmaxf(g[0], g[1]), fmaxf(g[2], g[3]));
        float se = 0.f;
        #pragma unroll
        for (int e = 0; e < 4; e++) { g[e] = __expf(g[e] - mx); se += g[e]; }
        #pragma unroll
        for (int e = 0; e < 4; e++) g[e] /= se;
        int i1 = 0; float v1 = g[0];
        #pragma unroll
        for (int e = 1; e < 4; e++) if (g[e] > v1) { v1 = g[e]; i1 = e; }
        int i2 = -1; float v2 = -1.f;
        #pragma unroll
        for (int e = 0; e < 4; e++) if (e != i1 && g[e] > v2) { v2 = g[e]; i2 = e; }
        float sw = fmaxf(v1 + v2, 1e-9f);
        float* wr = wts + (size_t)tk * 4;
        wr[0] = 0.f; wr[1] = 0.f; wr[2] = 0.f; wr[3] = 0.f;
        wr[i1] = v1 / sw; wr[i2] = v2 / sw;
        #pragma unroll
        for (int e = 0; e < 4; e++) atomicAdd(&auxb[e], g[e]);
        atomicAdd(&auxb[4 + i1], 1.0f);
        atomicAdd(&auxb[4 + i2], 1.0f);
    }
}

// ---------------- final: out = x_s + depthwise-conv5(Tr) + tb ----------------
__global__ __launch_bounds__(256) void final_k(
    const float* __restrict__ xs, const float* __restrict__ Tr,
    const float* __restrict__ tw, const float* __restrict__ tb, float* __restrict__ out)
{
    int n = blockIdx.x, b = blockIdx.y, t = threadIdx.x;
    for (int d = t; d < D_MODEL; d += 256) {
        float acc = tb[d];
        #pragma unroll
        for (int j = 0; j < 5; j++) {
            int i = n + j - 2;
            if (i >= 0 && i < SEQ)
                acc += Tr[((size_t)(b * SEQ + i)) * D_MODEL + d] * tw[d * 5 + j];
        }
        size_t idx = ((size_t)(b * SEQ + n)) * D_MODEL + d;
        out[idx] = xs[idx] + acc;
    }
}

__global__ void aux_k(const float* __restrict__ ab, float* __restrict__ out) {
    if (threadIdx.x == 0 && blockIdx.x == 0) {
        float a = 0.f;
        for (int e = 0; e < 4; e++)
            a += (ab[e] / (float)TOKENS) * (ab[4 + e] / (float)TOKENS);
        out[0] = 4.0f * a;
    }
}

extern "C" void kernel_launch(void* const* d_in, const int* in_sizes, int n_in,
                              void* d_out, int out_size, void* d_ws, size_t ws_size,
                              hipStream_t stream)
{
    const float* x    = (const float*)d_in[0];
    const float* qw   = (const float*)d_in[1];
    const float* qb   = (const float*)d_in[2];
    const float* kw   = (const float*)d_in[3];
    const float* kb   = (const float*)d_in[4];
    const float* vw   = (const float*)d_in[5];
    const float* vb   = (const float*)d_in[6];
    const float* ow   = (const float*)d_in[7];
    const float* ob   = (const float*)d_in[8];
    const float* n1g  = (const float*)d_in[9];
    const float* n1b  = (const float*)d_in[10];
    const float* n2g  = (const float*)d_in[11];
    const float* n2b  = (const float*)d_in[12];
    const float* alpha= (const float*)d_in[13];
    const float* dw7  = (const float*)d_in[14];
    const float* dw25 = (const float*)d_in[15];
    const float* dw49 = (const float*)d_in[16];
    const float* rw   = (const float*)d_in[17];
    const float* ew1  = (const float*)d_in[18];
    const float* eb1  = (const float*)d_in[19];
    const float* ew2  = (const float*)d_in[20];
    const float* eb2  = (const float*)d_in[21];
    const float* tw   = (const float*)d_in[22];
    const float* tb   = (const float*)d_in[23];

    char* ws = (char*)d_ws;
    const size_t MBy = 1ull << 20;
    float* S    = (float*)(ws + 0 * MBy);     // 32MB: seasonal -> x_s (in place)
    float* Tr   = (float*)(ws + 32 * MBy);    // 32MB: trend
    float* XF   = (float*)(ws + 64 * MBy);    // 32MB: LN2 out fp32 (router)
    bf16*  SNB  = (bf16*)(ws + 96 * MBy);     // 16MB: LN1 out bf16; reused for Y
    bf16*  QB   = (bf16*)(ws + 112 * MBy);    // 16MB (reused as H lower half)
    bf16*  KB   = (bf16*)(ws + 128 * MBy);    // 16MB (reused as H upper half)
    bf16*  VB   = (bf16*)(ws + 144 * MBy);    // 16MB
    bf16*  XFB  = (bf16*)(ws + 160 * MBy);    // 16MB: LN2 out bf16
    bf16*  WQ   = (bf16*)(ws + 176 * MBy);    // 2MB each
    bf16*  WK   = (bf16*)(ws + 178 * MBy);
    bf16*  WV   = (bf16*)(ws + 180 * MBy);
    bf16*  WO   = (bf16*)(ws + 182 * MBy);
    bf16*  WE1  = (bf16*)(ws + 184 * MBy);    // 16MB
    bf16*  WE2  = (bf16*)(ws + 200 * MBy);    // 16MB
    float* WTS  = (float*)(ws + 216 * MBy);   // [8192,4]
    float* AUXB = (float*)(ws + 217 * MBy);   // 8 floats
    bf16*  YB = SNB;
    bf16*  HB = QB;   // [8192,2048] spans QB+KB

    // weight conversion fp32 -> bf16
    f2b_k<<<2048, 256, 0, stream>>>(qw, WQ, D_MODEL * D_MODEL);
    f2b_k<<<2048, 256, 0, stream>>>(kw, WK, D_MODEL * D_MODEL);
    f2b_k<<<2048, 256, 0, stream>>>(vw, WV, D_MODEL * D_MODEL);
    f2b_k<<<2048, 256, 0, stream>>>(ow, WO, D_MODEL * D_MODEL);
    f2b_k<<<4096, 256, 0, stream>>>(ew1, WE1, 4 * MOE_H * D_MODEL);
    f2b_k<<<4096, 256, 0, stream>>>(ew2, WE2, 4 * D_MODEL * MOE_H);

    // decomposition
    decomp_k<<<dim3(SEQ, NB), 256, 0, stream>>>(x, alpha, dw7, dw25, dw49, Tr, S);

    // LN1 on seasonal
    ln_k<<<TOKENS, 256, 0, stream>>>(S, n1g, n1b, SNB, nullptr);

    // QKV projections (bf16 out)
    gemm_nt<0, 1><<<dim3(64, 8), 256, 0, stream>>>(SNB, WQ, qb, nullptr, nullptr, 0, QB, TOKENS, D_MODEL, D_MODEL);
    gemm_nt<0, 1><<<dim3(64, 8), 256, 0, stream>>>(SNB, WK, kb, nullptr, nullptr, 0, KB, TOKENS, D_MODEL, D_MODEL);
    gemm_nt<0, 1><<<dim3(64, 8), 256, 0, stream>>>(SNB, WV, vb, nullptr, nullptr, 0, VB, TOKENS, D_MODEL, D_MODEL);

    // attention
    attn_k<<<dim3(SEQ / 256, NHEAD, NB), 256, 0, stream>>>(QB, KB, VB, YB);

    // out projection + residual (x_s into S, in place)
    gemm_nt<0, 0><<<dim3(64, 8), 256, 0, stream>>>(YB, WO, ob, S, nullptr, 0, S, TOKENS, D_MODEL, D_MODEL);

    // LN2 (bf16 for GEMMs + fp32 for router)
    ln_k<<<TOKENS, 256, 0, stream>>>(S, n2g, n2b, XFB, XF);

    // router + aux accumulators
    hipMemsetAsync(AUXB, 0, 64, stream);
    router_k<<<TOKENS, 64, 0, stream>>>(XF, rw, WTS, AUXB);

    // dense 4-expert MoE, accumulated into x_s
    for (int e = 0; e < 4; e++) {
        gemm_nt<1, 1><<<dim3(64, 16), 256, 0, stream>>>(
            XFB, WE1 + (size_t)e * MOE_H * D_MODEL, eb1 + e * MOE_H,
            nullptr, nullptr, 0, HB, TOKENS, D_MODEL, MOE_H);
        gemm_nt<0, 2><<<dim3(64, 8), 256, 0, stream>>>(
            HB, WE2 + (size_t)e * D_MODEL * MOE_H, eb2 + e * D_MODEL,
            nullptr, WTS + e, 4, S, TOKENS, MOE_H, D_MODEL);
    }

    // final: out = x_s + conv5(Tr) + tb; aux scalar
    final_k<<<dim3(SEQ, NB), 256, 0, stream>>>(S, Tr, tw, tb, (float*)d_out);
    aux_k<<<1, 64, 0, stream>>>(AUXB, (float*)d_out + (out_size - 1));
}

// Round 2
// 2793.605 us; speedup vs baseline: 1.7692x; 1.7692x over previous
//
#include <hip/hip_runtime.h>
#include <hip/hip_bf16.h>
#include <math.h>

using bf16 = __hip_bfloat16;
typedef __attribute__((ext_vector_type(8))) short s8v;
typedef __attribute__((ext_vector_type(4))) float f32x4;

#define D_MODEL 1024
#define NB 8
#define SEQ 1024
#define NHEAD 16
#define HD 64
#define MOE_H 2048
#define TOKENS (NB*SEQ)

// ---------------- fp32 -> bf16 convert ----------------
__global__ void f2b_k(const float* __restrict__ in, bf16* __restrict__ out, int n) {
    int i = blockIdx.x * blockDim.x + threadIdx.x;
    int stride = gridDim.x * blockDim.x;
    for (; i < n; i += stride) out[i] = __float2bfloat16(in[i]);
}

// ---------------- decomposition: trend + seasonal (LDS-tiled stencil) ----------------
// grid: (n_chunks=8, d_chunks=16, b=8); block 256
#define TN 128
#define TD 64
__global__ __launch_bounds__(256) void decomp_k(
    const float* __restrict__ x, const float* __restrict__ alpha,
    const float* __restrict__ dw7, const float* __restrict__ dw25,
    const float* __restrict__ dw49, float* __restrict__ Tr, float* __restrict__ S)
{
    __shared__ float xs[TN + 48][TD];
    const int n0 = blockIdx.x * TN, d0 = blockIdx.y * TD, b = blockIdx.z;
    // stage x rows n0-24 .. n0+TN+23 (reflect at edges), coalesced float4
    for (int i = threadIdx.x; i < (TN + 48) * (TD / 4); i += 256) {
        int r = i / (TD / 4), c4 = (i % (TD / 4)) * 4;
        int n = n0 + r - 24;
        if (n < 0) n = -n;
        if (n > SEQ - 1) n = 2 * (SEQ - 1) - n;
        *(float4*)&xs[r][c4] =
            *(const float4*)&x[((size_t)(b * SEQ + n)) * D_MODEL + d0 + c4];
    }
    // softmax mixing weights
    float a0 = alpha[0], a1 = alpha[1], a2 = alpha[2];
    float mx = fmaxf(a0, fmaxf(a1, a2));
    float e0 = __expf(a0 - mx), e1 = __expf(a1 - mx), e2 = __expf(a2 - mx);
    float inv = 1.0f / (e0 + e1 + e2);
    float w7 = e0 * inv, w25 = e1 * inv, w49 = e2 * inv;
    // per-thread channel; fold the 3 kernels into one 49-tap kernel
    const int dl = threadIdx.x & 63;
    const int nt = threadIdx.x >> 6;
    const int d = d0 + dl;
    float w[49];
    #pragma unroll
    for (int j = 0; j < 49; j++) {
        float v = w49 * dw49[d * 49 + j];
        if (j >= 12 && j < 37) v += w25 * dw25[d * 25 + j - 12];
        if (j >= 21 && j < 28) v += w7 * dw7[d * 7 + j - 21];
        w[j] = v;
    }
    __syncthreads();
    for (int nl = nt; nl < TN; nl += 4) {
        float acc = 0.f;
        #pragma unroll
        for (int j = 0; j < 49; j++) acc = fmaf(xs[nl + j][dl], w[j], acc);
        size_t idx = ((size_t)(b * SEQ + n0 + nl)) * D_MODEL + d;
        Tr[idx] = acc;
        S[idx] = xs[nl + 24][dl] - acc;   // xs center == x at this position
    }
}

// ---------------- LayerNorm (fp32 in, bf16 out, optional fp32 out) ----------------
__global__ __launch_bounds__(256) void ln_k(
    const float* __restrict__ x, const float* __restrict__ g, const float* __restrict__ b,
    bf16* __restrict__ ob, float* __restrict__ of)
{
    int row = blockIdx.x, t = threadIdx.x;
    const float* xr = x + (size_t)row * D_MODEL;
    float s = 0.f, s2 = 0.f;
    for (int d = t; d < D_MODEL; d += 256) { float v = xr[d]; s += v; s2 += v * v; }
    #pragma unroll
    for (int o = 32; o > 0; o >>= 1) { s += __shfl_down(s, o); s2 += __shfl_down(s2, o); }
    __shared__ float sh[8];
    int wid = t >> 6, lane = t & 63;
    if (lane == 0) { sh[wid] = s; sh[4 + wid] = s2; }
    __syncthreads();
    if (t == 0) {
        float ts = sh[0] + sh[1] + sh[2] + sh[3];
        float t2 = sh[4] + sh[5] + sh[6] + sh[7];
        float m = ts / D_MODEL;
        float var = t2 / D_MODEL - m * m;
        sh[0] = m; sh[1] = rsqrtf(var + 1e-5f);
    }
    __syncthreads();
    float m = sh[0], rs = sh[1];
    for (int d = t; d < D_MODEL; d += 256) {
        float v = (xr[d] - m) * rs * g[d] + b[d];
        ob[(size_t)row * D_MODEL + d] = __float2bfloat16(v);
        if (of) of[(size_t)row * D_MODEL + d] = v;
    }
}

// ---------------- bf16 MFMA GEMM: C[M,O] = A[M,K] @ B[O,K]^T (+bias)(+act) ----------------
// OMODE 0: fp32 out (+optional residual), 1: bf16 out, 2: fp32 accumulate += rowscale*(v)
template<int ACT, int OMODE>
__global__ __launch_bounds__(256) void gemm_nt(
    const bf16* __restrict__ A, const bf16* __restrict__ B,
    const float* __restrict__ bias, const float* resid,
    const float* __restrict__ rowscale, int rs_stride,
    void* C, int M, int K, int O)
{
    __shared__ bf16 As[128][72];
    __shared__ bf16 Bs[128][72];
    const int t = threadIdx.x;
    const int bm = blockIdx.x, bn = blockIdx.y;
    const int lane = t & 63, wid = t >> 6;
    const int wm = wid >> 1, wn = wid & 1;
    f32x4 acc[4][4] = {};
    const int lr = t >> 3;          // 0..31 (staging row within pass)
    const int lc = (t & 7) * 8;     // 0,8,...,56 (staging col)
    const size_t abase = (size_t)(bm * 128) * K;
    const size_t bbase = (size_t)(bn * 128) * K;
    for (int k0 = 0; k0 < K; k0 += 64) {
        #pragma unroll
        for (int p = 0; p < 4; p++) {
            int r = p * 32 + lr;
            *(s8v*)&As[r][lc] = *(const s8v*)&A[abase + (size_t)r * K + k0 + lc];
            *(s8v*)&Bs[r][lc] = *(const s8v*)&B[bbase + (size_t)r * K + k0 + lc];
        }
        __syncthreads();
        const int fr = lane & 15, fq = (lane >> 4) * 8;
        #pragma unroll
        for (int kk = 0; kk < 64; kk += 32) {
            s8v af[4], bfr[4];
            #pragma unroll
            for (int i = 0; i < 4; i++) {
                af[i]  = *(const s8v*)&As[wm * 64 + i * 16 + fr][kk + fq];
                bfr[i] = *(const s8v*)&Bs[wn * 64 + i * 16 + fr][kk + fq];
            }
            #pragma unroll
            for (int i = 0; i < 4; i++)
                #pragma unroll
                for (int j = 0; j < 4; j++)
                    acc[i][j] = __builtin_amdgcn_mfma_f32_16x16x32_bf16(af[i], bfr[j], acc[i][j], 0, 0, 0);
        }
        __syncthreads();
    }
    const int cr = lane & 15, quad = lane >> 4;
    #pragma unroll
    for (int i = 0; i < 4; i++) {
        #pragma unroll
        for (int j = 0; j < 4; j++) {
            #pragma unroll
            for (int r = 0; r < 4; r++) {
                int row = bm * 128 + wm * 64 + i * 16 + quad * 4 + r;
                int col = bn * 128 + wn * 64 + j * 16 + cr;
                float v = acc[i][j][r];
                if (bias) v += bias[col];
                if (ACT == 1) v = 0.5f * v * (1.0f + erff(v * 0.70710678118f));
                size_t idx = (size_t)row * O + col;
                if (OMODE == 0) {
                    float rv = resid ? resid[idx] : 0.0f;
                    ((float*)C)[idx] = rv + v;
                } else if (OMODE == 1) {
                    ((bf16*)C)[idx] = __float2bfloat16(v);
                } else {
                    ((float*)C)[idx] += rowscale[(size_t)row * rs_stride] * v;
                }
            }
        }
    }
}

// ---------------- flash attention with ALiBi, fixed-shift softmax ----------------
__global__ __launch_bounds__(256) void attn_k(
    const bf16* __restrict__ Q, const bf16* __restrict__ K,
    const bf16* __restrict__ V, bf16* __restrict__ Y)
{
    __shared__ float Ks[64][68];
    __shared__ float Vs[64][68];
    int b = blockIdx.z, h = blockIdx.y;
    int qrow = blockIdx.x * 256 + threadIdx.x;
    float slope = exp2f(-0.5f * (float)(h + 1));
    float q[HD], o[HD];
    float l = 0.f;
    const bf16* qp = Q + ((size_t)(b * SEQ + qrow)) * D_MODEL + h * HD;
    #pragma unroll
    for (int d = 0; d < HD; d++) { q[d] = __bfloat162float(qp[d]); o[d] = 0.f; }
    for (int k0 = 0; k0 < SEQ; k0 += 64) {
        __syncthreads();
        for (int i = threadIdx.x; i < 64 * 64; i += 256) {
            int r = i >> 6, c = i & 63;
            size_t gk = ((size_t)(b * SEQ + k0 + r)) * D_MODEL + h * HD + c;
            Ks[r][c] = __bfloat162float(K[gk]);
            Vs[r][c] = __bfloat162float(V[gk]);
        }
        __syncthreads();
        for (int kk = 0; kk < 64; kk++) {
            float s = 0.f;
            const float4* kr = (const float4*)&Ks[kk][0];
            #pragma unroll
            for (int d4 = 0; d4 < 16; d4++) {
                float4 kv = kr[d4];
                s = fmaf(q[4 * d4 + 0], kv.x, s);
                s = fmaf(q[4 * d4 + 1], kv.y, s);
                s = fmaf(q[4 * d4 + 2], kv.z, s);
                s = fmaf(q[4 * d4 + 3], kv.w, s);
            }
            int kg = k0 + kk;
            float dist = (kg > qrow) ? (float)(kg - qrow) : 0.0f;
            float p = __expf(s * 0.125f - slope * dist - 8.0f);
            l += p;
            const float4* vr = (const float4*)&Vs[kk][0];
            #pragma unroll
            for (int d4 = 0; d4 < 16; d4++) {
                float4 vv = vr[d4];
                o[4 * d4 + 0] = fmaf(p, vv.x, o[4 * d4 + 0]);
                o[4 * d4 + 1] = fmaf(p, vv.y, o[4 * d4 + 1]);
                o[4 * d4 + 2] = fmaf(p, vv.z, o[4 * d4 + 2]);
                o[4 * d4 + 3] = fmaf(p, vv.w, o[4 * d4 + 3]);
            }
        }
    }
    float invl = 1.0f / l;
    bf16* yp = Y + ((size_t)(b * SEQ + qrow)) * D_MODEL + h * HD;
    #pragma unroll
    for (int d = 0; d < HD; d++) yp[d] = __float2bfloat16(o[d] * invl);
}

// ---------------- router: fp32 gates, top-2 weights, aux accumulators ----------------
__global__ __launch_bounds__(64) void router_k(
    const float* __restrict__ xf, const float* __restrict__ rw,
    float* __restrict__ wts, float* __restrict__ auxb)
{
    int tk = blockIdx.x, lane = threadIdx.x;
    const float* xr = xf + (size_t)tk * D_MODEL;
    float p0 = 0, p1 = 0, p2 = 0, p3 = 0;
    for (int d = lane; d < D_MODEL; d += 64) {
        float v = xr[d];
        p0 += v * rw[d];
        p1 += v * rw[D_MODEL + d];
        p2 += v * rw[2 * D_MODEL + d];
        p3 += v * rw[3 * D_MODEL + d];
    }
    #pragma unroll
    for (int o = 32; o > 0; o >>= 1) {
        p0 += __shfl_down(p0, o); p1 += __shfl_down(p1, o);
        p2 += __shfl_down(p2, o); p3 += __shfl_down(p3, o);
    }
    if (lane == 0) {
        float g[4] = { p0, p1, p2, p3 };
        float mx = fmaxf(fmaxf(g[0], g[1]), fmaxf(g[2], g[3]));
        float se = 0.f;
        #pragma unroll
        for (int e = 0; e < 4; e++) { g[e] = __expf(g[e] - mx); se += g[e]; }
        #pragma unroll
        for (int e = 0; e < 4; e++) g[e] /= se;
        int i1 = 0; float v1 = g[0];
        #pragma unroll
        for (int e = 1; e < 4; e++) if (g[e] > v1) { v1 = g[e]; i1 = e; }
        int i2 = -1; float v2 = -1.f;
        #pragma unroll
        for (int e = 0; e < 4; e++) if (e != i1 && g[e] > v2) { v2 = g[e]; i2 = e; }
        float sw = fmaxf(v1 + v2, 1e-9f);
        float* wr = wts + (size_t)tk * 4;
        wr[0] = 0.f; wr[1] = 0.f; wr[2] = 0.f; wr[3] = 0.f;
        wr[i1] = v1 / sw; wr[i2] = v2 / sw;
        #pragma unroll
        for (int e = 0; e < 4; e++) atomicAdd(&auxb[e], g[e]);
        atomicAdd(&auxb[4 + i1], 1.0f);
        atomicAdd(&auxb[4 + i2], 1.0f);
    }
}

// ---------------- final: out = x_s + depthwise-conv5(Tr) + tb ----------------
__global__ __launch_bounds__(256) void final_k(
    const float* __restrict__ xs, const float* __restrict__ Tr,
    const float* __restrict__ tw, const float* __restrict__ tb, float* __restrict__ out)
{
    int n = blockIdx.x, b = blockIdx.y, t = threadIdx.x;
    for (int d = t; d < D_MODEL; d += 256) {
        float acc = tb[d];
        #pragma unroll
        for (int j = 0; j < 5; j++) {
            int i = n + j - 2;
            if (i >= 0 && i < SEQ)
                acc += Tr[((size_t)(b * SEQ + i)) * D_MODEL + d] * tw[d * 5 + j];
        }
        size_t idx = ((size_t)(b * SEQ + n)) * D_MODEL + d;
        out[idx] = xs[idx] + acc;
    }
}

__global__ void aux_k(const float* __restrict__ ab, float* __restrict__ out) {
    if (threadIdx.x == 0 && blockIdx.x == 0) {
        float a = 0.f;
        for (int e = 0; e < 4; e++)
            a += (ab[e] / (float)TOKENS) * (ab[4 + e] / (float)TOKENS);
        out[0] = 4.0f * a;
    }
}

extern "C" void kernel_launch(void* const* d_in, const int* in_sizes, int n_in,
                              void* d_out, int out_size, void* d_ws, size_t ws_size,
                              hipStream_t stream)
{
    const float* x    = (const float*)d_in[0];
    const float* qw   = (const float*)d_in[1];
    const float* qb   = (const float*)d_in[2];
    const float* kw   = (const float*)d_in[3];
    const float* kb   = (const float*)d_in[4];
    const float* vw   = (const float*)d_in[5];
    const float* vb   = (const float*)d_in[6];
    const float* ow   = (const float*)d_in[7];
    const float* ob   = (const float*)d_in[8];
    const float* n1g  = (const float*)d_in[9];
    const float* n1b  = (const float*)d_in[10];
    const float* n2g  = (const float*)d_in[11];
    const float* n2b  = (const float*)d_in[12];
    const float* alpha= (const float*)d_in[13];
    const float* dw7  = (const float*)d_in[14];
    const float* dw25 = (const float*)d_in[15];
    const float* dw49 = (const float*)d_in[16];
    const float* rw   = (const float*)d_in[17];
    const float* ew1  = (const float*)d_in[18];
    const float* eb1  = (const float*)d_in[19];
    const float* ew2  = (const float*)d_in[20];
    const float* eb2  = (const float*)d_in[21];
    const float* tw   = (const float*)d_in[22];
    const float* tb   = (const float*)d_in[23];

    char* ws = (char*)d_ws;
    const size_t MBy = 1ull << 20;
    float* S    = (float*)(ws + 0 * MBy);     // 32MB: seasonal -> x_s (in place)
    float* Tr   = (float*)(ws + 32 * MBy);    // 32MB: trend
    float* XF   = (float*)(ws + 64 * MBy);    // 32MB: LN2 out fp32 (router)
    bf16*  SNB  = (bf16*)(ws + 96 * MBy);     // 16MB: LN1 out bf16; reused for Y
    bf16*  QB   = (bf16*)(ws + 112 * MBy);    // 16MB (reused as H lower half)
    bf16*  KB   = (bf16*)(ws + 128 * MBy);    // 16MB (reused as H upper half)
    bf16*  VB   = (bf16*)(ws + 144 * MBy);    // 16MB
    bf16*  XFB  = (bf16*)(ws + 160 * MBy);    // 16MB: LN2 out bf16
    bf16*  WQ   = (bf16*)(ws + 176 * MBy);    // 2MB each
    bf16*  WK   = (bf16*)(ws + 178 * MBy);
    bf16*  WV   = (bf16*)(ws + 180 * MBy);
    bf16*  WO   = (bf16*)(ws + 182 * MBy);
    bf16*  WE1  = (bf16*)(ws + 184 * MBy);    // 16MB
    bf16*  WE2  = (bf16*)(ws + 200 * MBy);    // 16MB
    float* WTS  = (float*)(ws + 216 * MBy);   // [8192,4]
    float* AUXB = (float*)(ws + 217 * MBy);   // 8 floats
    bf16*  YB = SNB;
    bf16*  HB = QB;   // [8192,2048] spans QB+KB

    // weight conversion fp32 -> bf16
    f2b_k<<<2048, 256, 0, stream>>>(qw, WQ, D_MODEL * D_MODEL);
    f2b_k<<<2048, 256, 0, stream>>>(kw, WK, D_MODEL * D_MODEL);
    f2b_k<<<2048, 256, 0, stream>>>(vw, WV, D_MODEL * D_MODEL);
    f2b_k<<<2048, 256, 0, stream>>>(ow, WO, D_MODEL * D_MODEL);
    f2b_k<<<4096, 256, 0, stream>>>(ew1, WE1, 4 * MOE_H * D_MODEL);
    f2b_k<<<4096, 256, 0, stream>>>(ew2, WE2, 4 * D_MODEL * MOE_H);

    // decomposition (LDS-tiled stencil)
    decomp_k<<<dim3(SEQ / TN, D_MODEL / TD, NB), 256, 0, stream>>>(x, alpha, dw7, dw25, dw49, Tr, S);

    // LN1 on seasonal
    ln_k<<<TOKENS, 256, 0, stream>>>(S, n1g, n1b, SNB, nullptr);

    // QKV projections (bf16 out)
    gemm_nt<0, 1><<<dim3(64, 8), 256, 0, stream>>>(SNB, WQ, qb, nullptr, nullptr, 0, QB, TOKENS, D_MODEL, D_MODEL);
    gemm_nt<0, 1><<<dim3(64, 8), 256, 0, stream>>>(SNB, WK, kb, nullptr, nullptr, 0, KB, TOKENS, D_MODEL, D_MODEL);
    gemm_nt<0, 1><<<dim3(64, 8), 256, 0, stream>>>(SNB, WV, vb, nullptr, nullptr, 0, VB, TOKENS, D_MODEL, D_MODEL);

    // attention
    attn_k<<<dim3(SEQ / 256, NHEAD, NB), 256, 0, stream>>>(QB, KB, VB, YB);

    // out projection + residual (x_s into S, in place)
    gemm_nt<0, 0><<<dim3(64, 8), 256, 0, stream>>>(YB, WO, ob, S, nullptr, 0, S, TOKENS, D_MODEL, D_MODEL);

    // LN2 (bf16 for GEMMs + fp32 for router)
    ln_k<<<TOKENS, 256, 0, stream>>>(S, n2g, n2b, XFB, XF);

    // router + aux accumulators
    hipMemsetAsync(AUXB, 0, 64, stream);
    router_k<<<TOKENS, 64, 0, stream>>>(XF, rw, WTS, AUXB);

    // dense 4-expert MoE, accumulated into x_s
    for (int e = 0; e < 4; e++) {
        gemm_nt<1, 1><<<dim3(64, 16), 256, 0, stream>>>(
            XFB, WE1 + (size_t)e * MOE_H * D_MODEL, eb1 + e * MOE_H,
            nullptr, nullptr, 0, HB, TOKENS, D_MODEL, MOE_H);
        gemm_nt<0, 2><<<dim3(64, 8), 256, 0, stream>>>(
            HB, WE2 + (size_t)e * D_MODEL * MOE_H, eb2 + e * D_MODEL,
            nullptr, WTS + e, 4, S, TOKENS, MOE_H, D_MODEL);
    }

    // final: out = x_s + conv5(Tr) + tb; aux scalar
    final_k<<<dim3(SEQ, NB), 256, 0, stream>>>(S, Tr, tw, tb, (float*)d_out);
    aux_k<<<1, 64, 0, stream>>>(AUXB, (float*)d_out + (out_size - 1));
}

// Round 3
// 1799.953 us; speedup vs baseline: 2.7458x; 1.5520x over previous
//
#include <hip/hip_runtime.h>
#include <hip/hip_bf16.h>
#include <math.h>

using bf16 = __hip_bfloat16;
typedef __attribute__((ext_vector_type(8))) short s8v;
typedef __attribute__((ext_vector_type(4))) float f32x4;

#define D_MODEL 1024
#define NB 8
#define SEQ 1024
#define NHEAD 16
#define HD 64
#define MOE_H 2048
#define TOKENS (NB*SEQ)

// ---------------- fp32 -> bf16 convert ----------------
__global__ void f2b_k(const float* __restrict__ in, bf16* __restrict__ out, int n) {
    int i = blockIdx.x * blockDim.x + threadIdx.x;
    int stride = gridDim.x * blockDim.x;
    for (; i < n; i += stride) out[i] = __float2bfloat16(in[i]);
}

// ---------------- decomposition: trend + seasonal (LDS-tiled stencil) ----------------
#define TN 128
#define TD 64
__global__ __launch_bounds__(256) void decomp_k(
    const float* __restrict__ x, const float* __restrict__ alpha,
    const float* __restrict__ dw7, const float* __restrict__ dw25,
    const float* __restrict__ dw49, float* __restrict__ Tr, float* __restrict__ S)
{
    __shared__ float xs[TN + 48][TD];
    const int n0 = blockIdx.x * TN, d0 = blockIdx.y * TD, b = blockIdx.z;
    for (int i = threadIdx.x; i < (TN + 48) * (TD / 4); i += 256) {
        int r = i / (TD / 4), c4 = (i % (TD / 4)) * 4;
        int n = n0 + r - 24;
        if (n < 0) n = -n;
        if (n > SEQ - 1) n = 2 * (SEQ - 1) - n;
        *(float4*)&xs[r][c4] =
            *(const float4*)&x[((size_t)(b * SEQ + n)) * D_MODEL + d0 + c4];
    }
    float a0 = alpha[0], a1 = alpha[1], a2 = alpha[2];
    float mx = fmaxf(a0, fmaxf(a1, a2));
    float e0 = __expf(a0 - mx), e1 = __expf(a1 - mx), e2 = __expf(a2 - mx);
    float inv = 1.0f / (e0 + e1 + e2);
    float w7 = e0 * inv, w25 = e1 * inv, w49 = e2 * inv;
    const int dl = threadIdx.x & 63;
    const int nt = threadIdx.x >> 6;
    const int d = d0 + dl;
    float w[49];
    #pragma unroll
    for (int j = 0; j < 49; j++) {
        float v = w49 * dw49[d * 49 + j];
        if (j >= 12 && j < 37) v += w25 * dw25[d * 25 + j - 12];
        if (j >= 21 && j < 28) v += w7 * dw7[d * 7 + j - 21];
        w[j] = v;
    }
    __syncthreads();
    for (int nl = nt; nl < TN; nl += 4) {
        float acc = 0.f;
        #pragma unroll
        for (int j = 0; j < 49; j++) acc = fmaf(xs[nl + j][dl], w[j], acc);
        size_t idx = ((size_t)(b * SEQ + n0 + nl)) * D_MODEL + d;
        Tr[idx] = acc;
        S[idx] = xs[nl + 24][dl] - acc;
    }
}

// ---------------- LayerNorm (fp32 in, bf16 out, optional fp32 out) ----------------
__global__ __launch_bounds__(256) void ln_k(
    const float* __restrict__ x, const float* __restrict__ g, const float* __restrict__ b,
    bf16* __restrict__ ob, float* __restrict__ of)
{
    int row = blockIdx.x, t = threadIdx.x;
    const float* xr = x + (size_t)row * D_MODEL;
    float s = 0.f, s2 = 0.f;
    for (int d = t; d < D_MODEL; d += 256) { float v = xr[d]; s += v; s2 += v * v; }
    #pragma unroll
    for (int o = 32; o > 0; o >>= 1) { s += __shfl_down(s, o); s2 += __shfl_down(s2, o); }
    __shared__ float sh[8];
    int wid = t >> 6, lane = t & 63;
    if (lane == 0) { sh[wid] = s; sh[4 + wid] = s2; }
    __syncthreads();
    if (t == 0) {
        float ts = sh[0] + sh[1] + sh[2] + sh[3];
        float t2 = sh[4] + sh[5] + sh[6] + sh[7];
        float m = ts / D_MODEL;
        float var = t2 / D_MODEL - m * m;
        sh[0] = m; sh[1] = rsqrtf(var + 1e-5f);
    }
    __syncthreads();
    float m = sh[0], rs = sh[1];
    for (int d = t; d < D_MODEL; d += 256) {
        float v = (xr[d] - m) * rs * g[d] + b[d];
        ob[(size_t)row * D_MODEL + d] = __float2bfloat16(v);
        if (of) of[(size_t)row * D_MODEL + d] = v;
    }
}

// ---------------- bf16 MFMA GEMM: C[M,O] = A[M,K] @ B[O,K]^T (+bias)(+act) ----------------
template<int ACT, int OMODE>
__global__ __launch_bounds__(256) void gemm_nt(
    const bf16* __restrict__ A, const bf16* __restrict__ B,
    const float* __restrict__ bias, const float* resid,
    const float* __restrict__ rowscale, int rs_stride,
    void* C, int M, int K, int O)
{
    __shared__ bf16 As[128][72];
    __shared__ bf16 Bs[128][72];
    const int t = threadIdx.x;
    const int bm = blockIdx.x, bn = blockIdx.y;
    const int lane = t & 63, wid = t >> 6;
    const int wm = wid >> 1, wn = wid & 1;
    f32x4 acc[4][4] = {};
    const int lr = t >> 3;
    const int lc = (t & 7) * 8;
    const size_t abase = (size_t)(bm * 128) * K;
    const size_t bbase = (size_t)(bn * 128) * K;
    for (int k0 = 0; k0 < K; k0 += 64) {
        #pragma unroll
        for (int p = 0; p < 4; p++) {
            int r = p * 32 + lr;
            *(s8v*)&As[r][lc] = *(const s8v*)&A[abase + (size_t)r * K + k0 + lc];
            *(s8v*)&Bs[r][lc] = *(const s8v*)&B[bbase + (size_t)r * K + k0 + lc];
        }
        __syncthreads();
        const int fr = lane & 15, fq = (lane >> 4) * 8;
        #pragma unroll
        for (int kk = 0; kk < 64; kk += 32) {
            s8v af[4], bfr[4];
            #pragma unroll
            for (int i = 0; i < 4; i++) {
                af[i]  = *(const s8v*)&As[wm * 64 + i * 16 + fr][kk + fq];
                bfr[i] = *(const s8v*)&Bs[wn * 64 + i * 16 + fr][kk + fq];
            }
            #pragma unroll
            for (int i = 0; i < 4; i++)
                #pragma unroll
                for (int j = 0; j < 4; j++)
                    acc[i][j] = __builtin_amdgcn_mfma_f32_16x16x32_bf16(af[i], bfr[j], acc[i][j], 0, 0, 0);
        }
        __syncthreads();
    }
    const int cr = lane & 15, quad = lane >> 4;
    #pragma unroll
    for (int i = 0; i < 4; i++) {
        #pragma unroll
        for (int j = 0; j < 4; j++) {
            #pragma unroll
            for (int r = 0; r < 4; r++) {
                int row = bm * 128 + wm * 64 + i * 16 + quad * 4 + r;
                int col = bn * 128 + wn * 64 + j * 16 + cr;
                float v = acc[i][j][r];
                if (bias) v += bias[col];
                if (ACT == 1) v = 0.5f * v * (1.0f + erff(v * 0.70710678118f));
                size_t idx = (size_t)row * O + col;
                if (OMODE == 0) {
                    float rv = resid ? resid[idx] : 0.0f;
                    ((float*)C)[idx] = rv + v;
                } else if (OMODE == 1) {
                    ((bf16*)C)[idx] = __float2bfloat16(v);
                } else {
                    ((float*)C)[idx] += rowscale[(size_t)row * rs_stride] * v;
                }
            }
        }
    }
}

// ---------------- MFMA flash attention with ALiBi, fixed-shift softmax ----------------
// block: 256 thr = 4 waves, each wave owns 16 q-rows; K/V staged in 64-key tiles.
__global__ __launch_bounds__(256) void attn_k(
    const bf16* __restrict__ Q, const bf16* __restrict__ K,
    const bf16* __restrict__ V, bf16* __restrict__ Y)
{
    __shared__ bf16 Ks[64][72];     // [key][d], padded
    __shared__ bf16 Vt[64][66];     // [d][key], transposed, padded
    __shared__ bf16 Pw[4][16][68];  // per-wave P tile [q][key]
    const int t = threadIdx.x;
    const int wave = t >> 6, lane = t & 63;
    const int qm = lane & 15, quad = lane >> 4;
    const int b = blockIdx.z, h = blockIdx.y;
    const int qbase = blockIdx.x * 64 + wave * 16;
    const float slope = exp2f(-0.5f * (float)(h + 1));

    // Q fragments (A-layout: m=lane&15, k=quad*8+j), d-chunks 0-31 / 32-63
    const bf16* qp = Q + ((size_t)(b * SEQ + qbase + qm)) * D_MODEL + h * HD;
    const s8v qa0 = *(const s8v*)&qp[quad * 8];
    const s8v qa1 = *(const s8v*)&qp[32 + quad * 8];

    f32x4 o[4] = {};
    float l[4] = {0.f, 0.f, 0.f, 0.f};

    const int sr = t >> 2;            // staging key row 0..63
    const int scc = (t & 3) * 16;     // staging col 0,16,32,48

    for (int k0 = 0; k0 < SEQ; k0 += 64) {
        __syncthreads();
        const bf16* kp = K + ((size_t)(b * SEQ + k0 + sr)) * D_MODEL + h * HD + scc;
        const bf16* vp = V + ((size_t)(b * SEQ + k0 + sr)) * D_MODEL + h * HD + scc;
        s8v k0v = *(const s8v*)&kp[0];
        s8v k1v = *(const s8v*)&kp[8];
        s8v v0 = *(const s8v*)&vp[0];
        s8v v1 = *(const s8v*)&vp[8];
        *(s8v*)&Ks[sr][scc] = k0v;
        *(s8v*)&Ks[sr][scc + 8] = k1v;
        #pragma unroll
        for (int j = 0; j < 8; j++) {
            Vt[scc + j][sr]     = ((const bf16*)&v0)[j];
            Vt[scc + 8 + j][sr] = ((const bf16*)&v1)[j];
        }
        __syncthreads();
        // QK^T: 4 key n-tiles x (K=32 over d twice)
        f32x4 scr[4];
        #pragma unroll
        for (int jt = 0; jt < 4; jt++) {
            f32x4 z = {};
            s8v b0 = *(const s8v*)&Ks[jt * 16 + qm][quad * 8];
            s8v b1 = *(const s8v*)&Ks[jt * 16 + qm][32 + quad * 8];
            z = __builtin_amdgcn_mfma_f32_16x16x32_bf16(qa0, b0, z, 0, 0, 0);
            z = __builtin_amdgcn_mfma_f32_16x16x32_bf16(qa1, b1, z, 0, 0, 0);
            scr[jt] = z;
        }
        // p = exp(s/8 - slope*dist - 8); write C-layout -> LDS (A-layout readback)
        #pragma unroll
        for (int jt = 0; jt < 4; jt++) {
            int kcol = k0 + jt * 16 + qm;
            #pragma unroll
            for (int r = 0; r < 4; r++) {
                int qrow = qbase + quad * 4 + r;
                float dist = (float)max(kcol - qrow, 0);
                float pf = __expf(fmaf(scr[jt][r], 0.125f, fmaf(-slope, dist, -8.0f)));
                bf16 pb = __float2bfloat16(pf);
                l[r] += __bfloat162float(pb);
                Pw[wave][quad * 4 + r][jt * 16 + qm] = pb;
            }
        }
        __builtin_amdgcn_wave_barrier();
        // PV: contraction over 64 keys (2 A-frags), 4 d n-tiles
        s8v pa0 = *(const s8v*)&Pw[wave][qm][quad * 8];
        s8v pa1 = *(const s8v*)&Pw[wave][qm][32 + quad * 8];
        #pragma unroll
        for (int dt = 0; dt < 4; dt++) {
            s8v vb0 = *(const s8v*)&Vt[dt * 16 + qm][quad * 8];
            s8v vb1 = *(const s8v*)&Vt[dt * 16 + qm][32 + quad * 8];
            o[dt] = __builtin_amdgcn_mfma_f32_16x16x32_bf16(pa0, vb0, o[dt], 0, 0, 0);
            o[dt] = __builtin_amdgcn_mfma_f32_16x16x32_bf16(pa1, vb1, o[dt], 0, 0, 0);
        }
    }
    // row sums: reduce over the 16 col-lanes of each quad group
    #pragma unroll
    for (int r = 0; r < 4; r++) {
        float s = l[r];
        s += __shfl_xor(s, 1); s += __shfl_xor(s, 2);
        s += __shfl_xor(s, 4); s += __shfl_xor(s, 8);
        l[r] = 1.0f / s;
    }
    #pragma unroll
    for (int dt = 0; dt < 4; dt++)
        #pragma unroll
        for (int r = 0; r < 4; r++) {
            size_t idx = ((size_t)(b * SEQ + qbase + quad * 4 + r)) * D_MODEL + h * HD + dt * 16 + qm;
            Y[idx] = __float2bfloat16(o[dt][r] * l[r]);
        }
}

// ---------------- router: fp32 gates, top-2 weights, aux accumulators ----------------
__global__ __launch_bounds__(64) void router_k(
    const float* __restrict__ xf, const float* __restrict__ rw,
    float* __restrict__ wts, float* __restrict__ auxb)
{
    int tk = blockIdx.x, lane = threadIdx.x;
    const float* xr = xf + (size_t)tk * D_MODEL;
    float p0 = 0, p1 = 0, p2 = 0, p3 = 0;
    for (int d = lane; d < D_MODEL; d += 64) {
        float v = xr[d];
        p0 += v * rw[d];
        p1 += v * rw[D_MODEL + d];
        p2 += v * rw[2 * D_MODEL + d];
        p3 += v * rw[3 * D_MODEL + d];
    }
    #pragma unroll
    for (int o = 32; o > 0; o >>= 1) {
        p0 += __shfl_down(p0, o); p1 += __shfl_down(p1, o);
        p2 += __shfl_down(p2, o); p3 += __shfl_down(p3, o);
    }
    if (lane == 0) {
        float g[4] = { p0, p1, p2, p3 };
        float mx = fmaxf(fmaxf(g[0], g[1]), fmaxf(g[2], g[3]));
        float se = 0.f;
        #pragma unroll
        for (int e = 0; e < 4; e++) { g[e] = __expf(g[e] - mx); se += g[e]; }
        #pragma unroll
        for (int e = 0; e < 4; e++) g[e] /= se;
        int i1 = 0; float v1 = g[0];
        #pragma unroll
        for (int e = 1; e < 4; e++) if (g[e] > v1) { v1 = g[e]; i1 = e; }
        int i2 = -1; float v2 = -1.f;
        #pragma unroll
        for (int e = 0; e < 4; e++) if (e != i1 && g[e] > v2) { v2 = g[e]; i2 = e; }
        float sw = fmaxf(v1 + v2, 1e-9f);
        float* wr = wts + (size_t)tk * 4;
        wr[0] = 0.f; wr[1] = 0.f; wr[2] = 0.f; wr[3] = 0.f;
        wr[i1] = v1 / sw; wr[i2] = v2 / sw;
        #pragma unroll
        for (int e = 0; e < 4; e++) atomicAdd(&auxb[e], g[e]);
        atomicAdd(&auxb[4 + i1], 1.0f);
        atomicAdd(&auxb[4 + i2], 1.0f);
    }
}

// ---------------- final: out = x_s + depthwise-conv5(Tr) + tb ----------------
__global__ __launch_bounds__(256) void final_k(
    const float* __restrict__ xs, const float* __restrict__ Tr,
    const float* __restrict__ tw, const float* __restrict__ tb, float* __restrict__ out)
{
    int n = blockIdx.x, b = blockIdx.y, t = threadIdx.x;
    for (int d = t; d < D_MODEL; d += 256) {
        float acc = tb[d];
        #pragma unroll
        for (int j = 0; j < 5; j++) {
            int i = n + j - 2;
            if (i >= 0 && i < SEQ)
                acc += Tr[((size_t)(b * SEQ + i)) * D_MODEL + d] * tw[d * 5 + j];
        }
        size_t idx = ((size_t)(b * SEQ + n)) * D_MODEL + d;
        out[idx] = xs[idx] + acc;
    }
}

__global__ void aux_k(const float* __restrict__ ab, float* __restrict__ out) {
    if (threadIdx.x == 0 && blockIdx.x == 0) {
        float a = 0.f;
        for (int e = 0; e < 4; e++)
            a += (ab[e] / (float)TOKENS) * (ab[4 + e] / (float)TOKENS);
        out[0] = 4.0f * a;
    }
}

extern "C" void kernel_launch(void* const* d_in, const int* in_sizes, int n_in,
                              void* d_out, int out_size, void* d_ws, size_t ws_size,
                              hipStream_t stream)
{
    const float* x    = (const float*)d_in[0];
    const float* qw   = (const float*)d_in[1];
    const float* qb   = (const float*)d_in[2];
    const float* kw   = (const float*)d_in[3];
    const float* kb   = (const float*)d_in[4];
    const float* vw   = (const float*)d_in[5];
    const float* vb   = (const float*)d_in[6];
    const float* ow   = (const float*)d_in[7];
    const float* ob   = (const float*)d_in[8];
    const float* n1g  = (const float*)d_in[9];
    const float* n1b  = (const float*)d_in[10];
    const float* n2g  = (const float*)d_in[11];
    const float* n2b  = (const float*)d_in[12];
    const float* alpha= (const float*)d_in[13];
    const float* dw7  = (const float*)d_in[14];
    const float* dw25 = (const float*)d_in[15];
    const float* dw49 = (const float*)d_in[16];
    const float* rw   = (const float*)d_in[17];
    const float* ew1  = (const float*)d_in[18];
    const float* eb1  = (const float*)d_in[19];
    const float* ew2  = (const float*)d_in[20];
    const float* eb2  = (const float*)d_in[21];
    const float* tw   = (const float*)d_in[22];
    const float* tb   = (const float*)d_in[23];

    char* ws = (char*)d_ws;
    const size_t MBy = 1ull << 20;
    float* S    = (float*)(ws + 0 * MBy);
    float* Tr   = (float*)(ws + 32 * MBy);
    float* XF   = (float*)(ws + 64 * MBy);
    bf16*  SNB  = (bf16*)(ws + 96 * MBy);
    bf16*  QB   = (bf16*)(ws + 112 * MBy);
    bf16*  KB   = (bf16*)(ws + 128 * MBy);
    bf16*  VB   = (bf16*)(ws + 144 * MBy);
    bf16*  XFB  = (bf16*)(ws + 160 * MBy);
    bf16*  WQ   = (bf16*)(ws + 176 * MBy);
    bf16*  WK   = (bf16*)(ws + 178 * MBy);
    bf16*  WV   = (bf16*)(ws + 180 * MBy);
    bf16*  WO   = (bf16*)(ws + 182 * MBy);
    bf16*  WE1  = (bf16*)(ws + 184 * MBy);
    bf16*  WE2  = (bf16*)(ws + 200 * MBy);
    float* WTS  = (float*)(ws + 216 * MBy);
    float* AUXB = (float*)(ws + 217 * MBy);
    bf16*  YB = SNB;
    bf16*  HB = QB;

    f2b_k<<<2048, 256, 0, stream>>>(qw, WQ, D_MODEL * D_MODEL);
    f2b_k<<<2048, 256, 0, stream>>>(kw, WK, D_MODEL * D_MODEL);
    f2b_k<<<2048, 256, 0, stream>>>(vw, WV, D_MODEL * D_MODEL);
    f2b_k<<<2048, 256, 0, stream>>>(ow, WO, D_MODEL * D_MODEL);
    f2b_k<<<4096, 256, 0, stream>>>(ew1, WE1, 4 * MOE_H * D_MODEL);
    f2b_k<<<4096, 256, 0, stream>>>(ew2, WE2, 4 * D_MODEL * MOE_H);

    decomp_k<<<dim3(SEQ / TN, D_MODEL / TD, NB), 256, 0, stream>>>(x, alpha, dw7, dw25, dw49, Tr, S);

    ln_k<<<TOKENS, 256, 0, stream>>>(S, n1g, n1b, SNB, nullptr);

    gemm_nt<0, 1><<<dim3(64, 8), 256, 0, stream>>>(SNB, WQ, qb, nullptr, nullptr, 0, QB, TOKENS, D_MODEL, D_MODEL);
    gemm_nt<0, 1><<<dim3(64, 8), 256, 0, stream>>>(SNB, WK, kb, nullptr, nullptr, 0, KB, TOKENS, D_MODEL, D_MODEL);
    gemm_nt<0, 1><<<dim3(64, 8), 256, 0, stream>>>(SNB, WV, vb, nullptr, nullptr, 0, VB, TOKENS, D_MODEL, D_MODEL);

    attn_k<<<dim3(SEQ / 64, NHEAD, NB), 256, 0, stream>>>(QB, KB, VB, YB);

    gemm_nt<0, 0><<<dim3(64, 8), 256, 0, stream>>>(YB, WO, ob, S, nullptr, 0, S, TOKENS, D_MODEL, D_MODEL);

    ln_k<<<TOKENS, 256, 0, stream>>>(S, n2g, n2b, XFB, XF);

    hipMemsetAsync(AUXB, 0, 64, stream);
    router_k<<<TOKENS, 64, 0, stream>>>(XF, rw, WTS, AUXB);

    for (int e = 0; e < 4; e++) {
        gemm_nt<1, 1><<<dim3(64, 16), 256, 0, stream>>>(
            XFB, WE1 + (size_t)e * MOE_H * D_MODEL, eb1 + e * MOE_H,
            nullptr, nullptr, 0, HB, TOKENS, D_MODEL, MOE_H);
        gemm_nt<0, 2><<<dim3(64, 8), 256, 0, stream>>>(
            HB, WE2 + (size_t)e * D_MODEL * MOE_H, eb2 + e * D_MODEL,
            nullptr, WTS + e, 4, S, TOKENS, MOE_H, D_MODEL);
    }

    final_k<<<dim3(SEQ, NB), 256, 0, stream>>>(S, Tr, tw, tb, (float*)d_out);
    aux_k<<<1, 64, 0, stream>>>(AUXB, (float*)d_out + (out_size - 1));
}

// Round 4
// 1149.530 us; speedup vs baseline: 4.2995x; 1.5658x over previous
//
#include <hip/hip_runtime.h>
#include <hip/hip_bf16.h>
#include <math.h>

using bf16 = __hip_bfloat16;
typedef __attribute__((ext_vector_type(8))) short s8v;
typedef __attribute__((ext_vector_type(4))) float f32x4;

#define D_MODEL 1024
#define NB 8
#define SEQ 1024
#define NHEAD 16
#define HD 64
#define MOE_H 2048
#define TOKENS (NB*SEQ)

// ---------------- fp32 -> bf16 convert ----------------
__global__ void f2b_k(const float* __restrict__ in, bf16* __restrict__ out, int n) {
    int i = blockIdx.x * blockDim.x + threadIdx.x;
    int stride = gridDim.x * blockDim.x;
    for (; i < n; i += stride) out[i] = __float2bfloat16(in[i]);
}

// ---------------- decomposition: trend + seasonal (LDS-tiled stencil) ----------------
#define TN 128
#define TD 64
__global__ __launch_bounds__(256) void decomp_k(
    const float* __restrict__ x, const float* __restrict__ alpha,
    const float* __restrict__ dw7, const float* __restrict__ dw25,
    const float* __restrict__ dw49, float* __restrict__ Tr, float* __restrict__ S)
{
    __shared__ float xs[TN + 48][TD];
    const int n0 = blockIdx.x * TN, d0 = blockIdx.y * TD, b = blockIdx.z;
    for (int i = threadIdx.x; i < (TN + 48) * (TD / 4); i += 256) {
        int r = i / (TD / 4), c4 = (i % (TD / 4)) * 4;
        int n = n0 + r - 24;
        if (n < 0) n = -n;
        if (n > SEQ - 1) n = 2 * (SEQ - 1) - n;
        *(float4*)&xs[r][c4] =
            *(const float4*)&x[((size_t)(b * SEQ + n)) * D_MODEL + d0 + c4];
    }
    float a0 = alpha[0], a1 = alpha[1], a2 = alpha[2];
    float mx = fmaxf(a0, fmaxf(a1, a2));
    float e0 = __expf(a0 - mx), e1 = __expf(a1 - mx), e2 = __expf(a2 - mx);
    float inv = 1.0f / (e0 + e1 + e2);
    float w7 = e0 * inv, w25 = e1 * inv, w49 = e2 * inv;
    const int dl = threadIdx.x & 63;
    const int nt = threadIdx.x >> 6;
    const int d = d0 + dl;
    float w[49];
    #pragma unroll
    for (int j = 0; j < 49; j++) {
        float v = w49 * dw49[d * 49 + j];
        if (j >= 12 && j < 37) v += w25 * dw25[d * 25 + j - 12];
        if (j >= 21 && j < 28) v += w7 * dw7[d * 7 + j - 21];
        w[j] = v;
    }
    __syncthreads();
    for (int nl = nt; nl < TN; nl += 4) {
        float acc = 0.f;
        #pragma unroll
        for (int j = 0; j < 49; j++) acc = fmaf(xs[nl + j][dl], w[j], acc);
        size_t idx = ((size_t)(b * SEQ + n0 + nl)) * D_MODEL + d;
        Tr[idx] = acc;
        S[idx] = xs[nl + 24][dl] - acc;
    }
}

// ---------------- LayerNorm (fp32 in, bf16 out, optional fp32 out) ----------------
__global__ __launch_bounds__(256) void ln_k(
    const float* __restrict__ x, const float* __restrict__ g, const float* __restrict__ b,
    bf16* __restrict__ ob, float* __restrict__ of)
{
    int row = blockIdx.x, t = threadIdx.x;
    const float* xr = x + (size_t)row * D_MODEL;
    float s = 0.f, s2 = 0.f;
    for (int d = t; d < D_MODEL; d += 256) { float v = xr[d]; s += v; s2 += v * v; }
    #pragma unroll
    for (int o = 32; o > 0; o >>= 1) { s += __shfl_down(s, o); s2 += __shfl_down(s2, o); }
    __shared__ float sh[8];
    int wid = t >> 6, lane = t & 63;
    if (lane == 0) { sh[wid] = s; sh[4 + wid] = s2; }
    __syncthreads();
    if (t == 0) {
        float ts = sh[0] + sh[1] + sh[2] + sh[3];
        float t2 = sh[4] + sh[5] + sh[6] + sh[7];
        float m = ts / D_MODEL;
        float var = t2 / D_MODEL - m * m;
        sh[0] = m; sh[1] = rsqrtf(var + 1e-5f);
    }
    __syncthreads();
    float m = sh[0], rs = sh[1];
    for (int d = t; d < D_MODEL; d += 256) {
        float v = (xr[d] - m) * rs * g[d] + b[d];
        ob[(size_t)row * D_MODEL + d] = __float2bfloat16(v);
        if (of) of[(size_t)row * D_MODEL + d] = v;
    }
}

// ---------------- bf16 MFMA GEMM: C[M,O] = A[M,K] @ B[O,K]^T (+bias)(+act) ----------------
template<int ACT, int OMODE>
__global__ __launch_bounds__(256) void gemm_nt(
    const bf16* __restrict__ A, const bf16* __restrict__ B,
    const float* __restrict__ bias, const float* resid,
    const float* __restrict__ rowscale, int rs_stride,
    void* C, int M, int K, int O)
{
    __shared__ bf16 As[128][72];
    __shared__ bf16 Bs[128][72];
    const int t = threadIdx.x;
    const int bm = blockIdx.x, bn = blockIdx.y;
    const int lane = t & 63, wid = t >> 6;
    const int wm = wid >> 1, wn = wid & 1;
    f32x4 acc[4][4] = {};
    const int lr = t >> 3;
    const int lc = (t & 7) * 8;
    const size_t abase = (size_t)(bm * 128) * K;
    const size_t bbase = (size_t)(bn * 128) * K;
    for (int k0 = 0; k0 < K; k0 += 64) {
        #pragma unroll
        for (int p = 0; p < 4; p++) {
            int r = p * 32 + lr;
            *(s8v*)&As[r][lc] = *(const s8v*)&A[abase + (size_t)r * K + k0 + lc];
            *(s8v*)&Bs[r][lc] = *(const s8v*)&B[bbase + (size_t)r * K + k0 + lc];
        }
        __syncthreads();
        const int fr = lane & 15, fq = (lane >> 4) * 8;
        #pragma unroll
        for (int kk = 0; kk < 64; kk += 32) {
            s8v af[4], bfr[4];
            #pragma unroll
            for (int i = 0; i < 4; i++) {
                af[i]  = *(const s8v*)&As[wm * 64 + i * 16 + fr][kk + fq];
                bfr[i] = *(const s8v*)&Bs[wn * 64 + i * 16 + fr][kk + fq];
            }
            #pragma unroll
            for (int i = 0; i < 4; i++)
                #pragma unroll
                for (int j = 0; j < 4; j++)
                    acc[i][j] = __builtin_amdgcn_mfma_f32_16x16x32_bf16(af[i], bfr[j], acc[i][j], 0, 0, 0);
        }
        __syncthreads();
    }
    const int cr = lane & 15, quad = lane >> 4;
    #pragma unroll
    for (int i = 0; i < 4; i++) {
        #pragma unroll
        for (int j = 0; j < 4; j++) {
            #pragma unroll
            for (int r = 0; r < 4; r++) {
                int row = bm * 128 + wm * 64 + i * 16 + quad * 4 + r;
                int col = bn * 128 + wn * 64 + j * 16 + cr;
                float v = acc[i][j][r];
                if (bias) v += bias[col];
                if (ACT == 1) v = 0.5f * v * (1.0f + erff(v * 0.70710678118f));
                size_t idx = (size_t)row * O + col;
                if (OMODE == 0) {
                    float rv = resid ? resid[idx] : 0.0f;
                    ((float*)C)[idx] = rv + v;
                } else if (OMODE == 1) {
                    ((bf16*)C)[idx] = __float2bfloat16(v);
                } else {
                    ((float*)C)[idx] += rowscale[(size_t)row * rs_stride] * v;
                }
            }
        }
    }
}

// ---------------- MFMA flash attention with ALiBi, fixed-shift softmax ----------------
__global__ __launch_bounds__(256) void attn_k(
    const bf16* __restrict__ Q, const bf16* __restrict__ K,
    const bf16* __restrict__ V, bf16* __restrict__ Y)
{
    __shared__ bf16 Ks[64][72];
    __shared__ bf16 Vt[64][66];
    __shared__ bf16 Pw[4][16][68];
    const int t = threadIdx.x;
    const int wave = t >> 6, lane = t & 63;
    const int qm = lane & 15, quad = lane >> 4;
    const int b = blockIdx.z, h = blockIdx.y;
    const int qbase = blockIdx.x * 64 + wave * 16;
    const float slope = exp2f(-0.5f * (float)(h + 1));

    const bf16* qp = Q + ((size_t)(b * SEQ + qbase + qm)) * D_MODEL + h * HD;
    const s8v qa0 = *(const s8v*)&qp[quad * 8];
    const s8v qa1 = *(const s8v*)&qp[32 + quad * 8];

    f32x4 o[4] = {};
    float l[4] = {0.f, 0.f, 0.f, 0.f};

    const int sr = t >> 2;
    const int scc = (t & 3) * 16;

    for (int k0 = 0; k0 < SEQ; k0 += 64) {
        __syncthreads();
        const bf16* kp = K + ((size_t)(b * SEQ + k0 + sr)) * D_MODEL + h * HD + scc;
        const bf16* vp = V + ((size_t)(b * SEQ + k0 + sr)) * D_MODEL + h * HD + scc;
        s8v k0v = *(const s8v*)&kp[0];
        s8v k1v = *(const s8v*)&kp[8];
        s8v v0 = *(const s8v*)&vp[0];
        s8v v1 = *(const s8v*)&vp[8];
        *(s8v*)&Ks[sr][scc] = k0v;
        *(s8v*)&Ks[sr][scc + 8] = k1v;
        #pragma unroll
        for (int j = 0; j < 8; j++) {
            Vt[scc + j][sr]     = ((const bf16*)&v0)[j];
            Vt[scc + 8 + j][sr] = ((const bf16*)&v1)[j];
        }
        __syncthreads();
        f32x4 scr[4];
        #pragma unroll
        for (int jt = 0; jt < 4; jt++) {
            f32x4 z = {};
            s8v b0 = *(const s8v*)&Ks[jt * 16 + qm][quad * 8];
            s8v b1 = *(const s8v*)&Ks[jt * 16 + qm][32 + quad * 8];
            z = __builtin_amdgcn_mfma_f32_16x16x32_bf16(qa0, b0, z, 0, 0, 0);
            z = __builtin_amdgcn_mfma_f32_16x16x32_bf16(qa1, b1, z, 0, 0, 0);
            scr[jt] = z;
        }
        #pragma unroll
        for (int jt = 0; jt < 4; jt++) {
            int kcol = k0 + jt * 16 + qm;
            #pragma unroll
            for (int r = 0; r < 4; r++) {
                int qrow = qbase + quad * 4 + r;
                float dist = (float)max(kcol - qrow, 0);
                float pf = __expf(fmaf(scr[jt][r], 0.125f, fmaf(-slope, dist, -8.0f)));
                bf16 pb = __float2bfloat16(pf);
                l[r] += __bfloat162float(pb);
                Pw[wave][quad * 4 + r][jt * 16 + qm] = pb;
            }
        }
        __builtin_amdgcn_wave_barrier();
        s8v pa0 = *(const s8v*)&Pw[wave][qm][quad * 8];
        s8v pa1 = *(const s8v*)&Pw[wave][qm][32 + quad * 8];
        #pragma unroll
        for (int dt = 0; dt < 4; dt++) {
            s8v vb0 = *(const s8v*)&Vt[dt * 16 + qm][quad * 8];
            s8v vb1 = *(const s8v*)&Vt[dt * 16 + qm][32 + quad * 8];
            o[dt] = __builtin_amdgcn_mfma_f32_16x16x32_bf16(pa0, vb0, o[dt], 0, 0, 0);
            o[dt] = __builtin_amdgcn_mfma_f32_16x16x32_bf16(pa1, vb1, o[dt], 0, 0, 0);
        }
    }
    #pragma unroll
    for (int r = 0; r < 4; r++) {
        float s = l[r];
        s += __shfl_xor(s, 1); s += __shfl_xor(s, 2);
        s += __shfl_xor(s, 4); s += __shfl_xor(s, 8);
        l[r] = 1.0f / s;
    }
    #pragma unroll
    for (int dt = 0; dt < 4; dt++)
        #pragma unroll
        for (int r = 0; r < 4; r++) {
            size_t idx = ((size_t)(b * SEQ + qbase + quad * 4 + r)) * D_MODEL + h * HD + dt * 16 + qm;
            Y[idx] = __float2bfloat16(o[dt][r] * l[r]);
        }
}

// ---------------- router: wave-per-token, block-reduced aux ----------------
// grid 512 x 256thr; wave handles 4 tokens, lane-parallel over d (16 ch/lane)
__global__ __launch_bounds__(256) void router_k(
    const float* __restrict__ xf, const float* __restrict__ rw,
    float* __restrict__ wts, float* __restrict__ auxb)
{
    const int wave = threadIdx.x >> 6, lane = threadIdx.x & 63;
    // preload router weights: 4 experts x 4 float4 per lane
    float4 w[4][4];
    #pragma unroll
    for (int e = 0; e < 4; e++)
        #pragma unroll
        for (int c = 0; c < 4; c++)
            w[e][c] = *(const float4*)&rw[e * D_MODEL + lane * 16 + c * 4];
    float ag[4] = {0.f, 0.f, 0.f, 0.f};
    float ac[4] = {0.f, 0.f, 0.f, 0.f};
    const int t0 = (blockIdx.x * 4 + wave) * 4;
    #pragma unroll
    for (int i = 0; i < 4; i++) {
        const int tk = t0 + i;
        const float* xr = xf + (size_t)tk * D_MODEL + lane * 16;
        float4 xv[4];
        #pragma unroll
        for (int c = 0; c < 4; c++) xv[c] = *(const float4*)&xr[c * 4];
        float p[4] = {0.f, 0.f, 0.f, 0.f};
        #pragma unroll
        for (int e = 0; e < 4; e++)
            #pragma unroll
            for (int c = 0; c < 4; c++) {
                p[e] = fmaf(xv[c].x, w[e][c].x, p[e]);
                p[e] = fmaf(xv[c].y, w[e][c].y, p[e]);
                p[e] = fmaf(xv[c].z, w[e][c].z, p[e]);
                p[e] = fmaf(xv[c].w, w[e][c].w, p[e]);
            }
        #pragma unroll
        for (int o = 1; o < 64; o <<= 1) {
            p[0] += __shfl_xor(p[0], o); p[1] += __shfl_xor(p[1], o);
            p[2] += __shfl_xor(p[2], o); p[3] += __shfl_xor(p[3], o);
        }
        // all lanes: softmax + top2 (identical fp32 math)
        float g[4];
        float mx = fmaxf(fmaxf(p[0], p[1]), fmaxf(p[2], p[3]));
        float se = 0.f;
        #pragma unroll
        for (int e = 0; e < 4; e++) { g[e] = __expf(p[e] - mx); se += g[e]; }
        #pragma unroll
        for (int e = 0; e < 4; e++) g[e] /= se;
        int i1 = 0; float v1 = g[0];
        #pragma unroll
        for (int e = 1; e < 4; e++) if (g[e] > v1) { v1 = g[e]; i1 = e; }
        int i2 = -1; float v2 = -1.f;
        #pragma unroll
        for (int e = 0; e < 4; e++) if (e != i1 && g[e] > v2) { v2 = g[e]; i2 = e; }
        float sw = fmaxf(v1 + v2, 1e-9f);
        if (lane < 4) {
            float wv = (lane == i1) ? v1 / sw : ((lane == i2) ? v2 / sw : 0.f);
            wts[(size_t)tk * 4 + lane] = wv;
        }
        if (lane == 0) {
            #pragma unroll
            for (int e = 0; e < 4; e++) ag[e] += g[e];
            ac[i1] += 1.f; ac[i2] += 1.f;
        }
    }
    // block-level aux reduce
    __shared__ float sh[4][8];
    if (lane == 0)
        #pragma unroll
        for (int e = 0; e < 4; e++) { sh[wave][e] = ag[e]; sh[wave][4 + e] = ac[e]; }
    __syncthreads();
    if (threadIdx.x < 8) {
        float s = sh[0][threadIdx.x] + sh[1][threadIdx.x] + sh[2][threadIdx.x] + sh[3][threadIdx.x];
        atomicAdd(&auxb[threadIdx.x], s);
    }
}

// ---------------- final: out = x_s + depthwise-conv5(Tr) + tb ----------------
__global__ __launch_bounds__(256) void final_k(
    const float* __restrict__ xs, const float* __restrict__ Tr,
    const float* __restrict__ tw, const float* __restrict__ tb, float* __restrict__ out)
{
    int n = blockIdx.x, b = blockIdx.y, t = threadIdx.x;
    for (int d = t; d < D_MODEL; d += 256) {
        float acc = tb[d];
        #pragma unroll
        for (int j = 0; j < 5; j++) {
            int i = n + j - 2;
            if (i >= 0 && i < SEQ)
                acc += Tr[((size_t)(b * SEQ + i)) * D_MODEL + d] * tw[d * 5 + j];
        }
        size_t idx = ((size_t)(b * SEQ + n)) * D_MODEL + d;
        out[idx] = xs[idx] + acc;
    }
}

__global__ void aux_k(const float* __restrict__ ab, float* __restrict__ out) {
    if (threadIdx.x == 0 && blockIdx.x == 0) {
        float a = 0.f;
        for (int e = 0; e < 4; e++)
            a += (ab[e] / (float)TOKENS) * (ab[4 + e] / (float)TOKENS);
        out[0] = 4.0f * a;
    }
}

extern "C" void kernel_launch(void* const* d_in, const int* in_sizes, int n_in,
                              void* d_out, int out_size, void* d_ws, size_t ws_size,
                              hipStream_t stream)
{
    const float* x    = (const float*)d_in[0];
    const float* qw   = (const float*)d_in[1];
    const float* qb   = (const float*)d_in[2];
    const float* kw   = (const float*)d_in[3];
    const float* kb   = (const float*)d_in[4];
    const float* vw   = (const float*)d_in[5];
    const float* vb   = (const float*)d_in[6];
    const float* ow   = (const float*)d_in[7];
    const float* ob   = (const float*)d_in[8];
    const float* n1g  = (const float*)d_in[9];
    const float* n1b  = (const float*)d_in[10];
    const float* n2g  = (const float*)d_in[11];
    const float* n2b  = (const float*)d_in[12];
    const float* alpha= (const float*)d_in[13];
    const float* dw7  = (const float*)d_in[14];
    const float* dw25 = (const float*)d_in[15];
    const float* dw49 = (const float*)d_in[16];
    const float* rw   = (const float*)d_in[17];
    const float* ew1  = (const float*)d_in[18];
    const float* eb1  = (const float*)d_in[19];
    const float* ew2  = (const float*)d_in[20];
    const float* eb2  = (const float*)d_in[21];
    const float* tw   = (const float*)d_in[22];
    const float* tb   = (const float*)d_in[23];

    char* ws = (char*)d_ws;
    const size_t MBy = 1ull << 20;
    float* S    = (float*)(ws + 0 * MBy);
    float* Tr   = (float*)(ws + 32 * MBy);
    float* XF   = (float*)(ws + 64 * MBy);
    bf16*  SNB  = (bf16*)(ws + 96 * MBy);
    bf16*  QB   = (bf16*)(ws + 112 * MBy);
    bf16*  KB   = (bf16*)(ws + 128 * MBy);
    bf16*  VB   = (bf16*)(ws + 144 * MBy);
    bf16*  XFB  = (bf16*)(ws + 160 * MBy);
    bf16*  WQ   = (bf16*)(ws + 176 * MBy);
    bf16*  WK   = (bf16*)(ws + 178 * MBy);
    bf16*  WV   = (bf16*)(ws + 180 * MBy);
    bf16*  WO   = (bf16*)(ws + 182 * MBy);
    bf16*  WE1  = (bf16*)(ws + 184 * MBy);
    bf16*  WE2  = (bf16*)(ws + 200 * MBy);
    float* WTS  = (float*)(ws + 216 * MBy);
    float* AUXB = (float*)(ws + 217 * MBy);
    bf16*  YB = SNB;
    bf16*  HB = QB;

    f2b_k<<<2048, 256, 0, stream>>>(qw, WQ, D_MODEL * D_MODEL);
    f2b_k<<<2048, 256, 0, stream>>>(kw, WK, D_MODEL * D_MODEL);
    f2b_k<<<2048, 256, 0, stream>>>(vw, WV, D_MODEL * D_MODEL);
    f2b_k<<<2048, 256, 0, stream>>>(ow, WO, D_MODEL * D_MODEL);
    f2b_k<<<4096, 256, 0, stream>>>(ew1, WE1, 4 * MOE_H * D_MODEL);
    f2b_k<<<4096, 256, 0, stream>>>(ew2, WE2, 4 * D_MODEL * MOE_H);

    decomp_k<<<dim3(SEQ / TN, D_MODEL / TD, NB), 256, 0, stream>>>(x, alpha, dw7, dw25, dw49, Tr, S);

    ln_k<<<TOKENS, 256, 0, stream>>>(S, n1g, n1b, SNB, nullptr);

    gemm_nt<0, 1><<<dim3(64, 8), 256, 0, stream>>>(SNB, WQ, qb, nullptr, nullptr, 0, QB, TOKENS, D_MODEL, D_MODEL);
    gemm_nt<0, 1><<<dim3(64, 8), 256, 0, stream>>>(SNB, WK, kb, nullptr, nullptr, 0, KB, TOKENS, D_MODEL, D_MODEL);
    gemm_nt<0, 1><<<dim3(64, 8), 256, 0, stream>>>(SNB, WV, vb, nullptr, nullptr, 0, VB, TOKENS, D_MODEL, D_MODEL);

    attn_k<<<dim3(SEQ / 64, NHEAD, NB), 256, 0, stream>>>(QB, KB, VB, YB);

    gemm_nt<0, 0><<<dim3(64, 8), 256, 0, stream>>>(YB, WO, ob, S, nullptr, 0, S, TOKENS, D_MODEL, D_MODEL);

    ln_k<<<TOKENS, 256, 0, stream>>>(S, n2g, n2b, XFB, XF);

    hipMemsetAsync(AUXB, 0, 64, stream);
    router_k<<<TOKENS / 16, 256, 0, stream>>>(XF, rw, WTS, AUXB);

    for (int e = 0; e < 4; e++) {
        gemm_nt<1, 1><<<dim3(64, 16), 256, 0, stream>>>(
            XFB, WE1 + (size_t)e * MOE_H * D_MODEL, eb1 + e * MOE_H,
            nullptr, nullptr, 0, HB, TOKENS, D_MODEL, MOE_H);
        gemm_nt<0, 2><<<dim3(64, 8), 256, 0, stream>>>(
            HB, WE2 + (size_t)e * D_MODEL * MOE_H, eb2 + e * D_MODEL,
            nullptr, WTS + e, 4, S, TOKENS, MOE_H, D_MODEL);
    }

    final_k<<<dim3(SEQ, NB), 256, 0, stream>>>(S, Tr, tw, tb, (float*)d_out);
    aux_k<<<1, 64, 0, stream>>>(AUXB, (float*)d_out + (out_size - 1));
}

// Round 5
// 1141.814 us; speedup vs baseline: 4.3285x; 1.0068x over previous
//
#include <hip/hip_runtime.h>
#include <hip/hip_bf16.h>
#include <math.h>

using bf16 = __hip_bfloat16;
typedef __attribute__((ext_vector_type(8))) short s8v;
typedef __attribute__((ext_vector_type(4))) float f32x4;

#define D_MODEL 1024
#define NB 8
#define SEQ 1024
#define NHEAD 16
#define HD 64
#define MOE_H 2048
#define TOKENS (NB*SEQ)

// ---------------- fp32 -> bf16 convert ----------------
__global__ void f2b_k(const float* __restrict__ in, bf16* __restrict__ out, int n) {
    int i = blockIdx.x * blockDim.x + threadIdx.x;
    int stride = gridDim.x * blockDim.x;
    for (; i < n; i += stride) out[i] = __float2bfloat16(in[i]);
}

// ---------------- decomposition: trend + seasonal (LDS-tiled stencil) ----------------
#define TN 128
#define TD 64
__global__ __launch_bounds__(256) void decomp_k(
    const float* __restrict__ x, const float* __restrict__ alpha,
    const float* __restrict__ dw7, const float* __restrict__ dw25,
    const float* __restrict__ dw49, float* __restrict__ Tr, float* __restrict__ S)
{
    __shared__ float xs[TN + 48][TD];
    const int n0 = blockIdx.x * TN, d0 = blockIdx.y * TD, b = blockIdx.z;
    for (int i = threadIdx.x; i < (TN + 48) * (TD / 4); i += 256) {
        int r = i / (TD / 4), c4 = (i % (TD / 4)) * 4;
        int n = n0 + r - 24;
        if (n < 0) n = -n;
        if (n > SEQ - 1) n = 2 * (SEQ - 1) - n;
        *(float4*)&xs[r][c4] =
            *(const float4*)&x[((size_t)(b * SEQ + n)) * D_MODEL + d0 + c4];
    }
    float a0 = alpha[0], a1 = alpha[1], a2 = alpha[2];
    float mx = fmaxf(a0, fmaxf(a1, a2));
    float e0 = __expf(a0 - mx), e1 = __expf(a1 - mx), e2 = __expf(a2 - mx);
    float inv = 1.0f / (e0 + e1 + e2);
    float w7 = e0 * inv, w25 = e1 * inv, w49 = e2 * inv;
    const int dl = threadIdx.x & 63;
    const int nt = threadIdx.x >> 6;
    const int d = d0 + dl;
    float w[49];
    #pragma unroll
    for (int j = 0; j < 49; j++) {
        float v = w49 * dw49[d * 49 + j];
        if (j >= 12 && j < 37) v += w25 * dw25[d * 25 + j - 12];
        if (j >= 21 && j < 28) v += w7 * dw7[d * 7 + j - 21];
        w[j] = v;
    }
    __syncthreads();
    for (int nl = nt; nl < TN; nl += 4) {
        float acc = 0.f;
        #pragma unroll
        for (int j = 0; j < 49; j++) acc = fmaf(xs[nl + j][dl], w[j], acc);
        size_t idx = ((size_t)(b * SEQ + n0 + nl)) * D_MODEL + d;
        Tr[idx] = acc;
        S[idx] = xs[nl + 24][dl] - acc;
    }
}

// ---------------- LayerNorm (fp32 in, bf16 out, optional fp32 out) ----------------
__global__ __launch_bounds__(256) void ln_k(
    const float* __restrict__ x, const float* __restrict__ g, const float* __restrict__ b,
    bf16* __restrict__ ob, float* __restrict__ of)
{
    int row = blockIdx.x, t = threadIdx.x;
    const float* xr = x + (size_t)row * D_MODEL;
    float s = 0.f, s2 = 0.f;
    for (int d = t; d < D_MODEL; d += 256) { float v = xr[d]; s += v; s2 += v * v; }
    #pragma unroll
    for (int o = 32; o > 0; o >>= 1) { s += __shfl_down(s, o); s2 += __shfl_down(s2, o); }
    __shared__ float sh[8];
    int wid = t >> 6, lane = t & 63;
    if (lane == 0) { sh[wid] = s; sh[4 + wid] = s2; }
    __syncthreads();
    if (t == 0) {
        float ts = sh[0] + sh[1] + sh[2] + sh[3];
        float t2 = sh[4] + sh[5] + sh[6] + sh[7];
        float m = ts / D_MODEL;
        float var = t2 / D_MODEL - m * m;
        sh[0] = m; sh[1] = rsqrtf(var + 1e-5f);
    }
    __syncthreads();
    float m = sh[0], rs = sh[1];
    for (int d = t; d < D_MODEL; d += 256) {
        float v = (xr[d] - m) * rs * g[d] + b[d];
        ob[(size_t)row * D_MODEL + d] = __float2bfloat16(v);
        if (of) of[(size_t)row * D_MODEL + d] = v;
    }
}

// ---------------- bf16 MFMA GEMM: C[M,O] = A[M,K] @ B[O,K]^T (+bias)(+act) ----------------
// OMODE 0: fp32 out (+resid), 1: bf16 out, 2: fp32 accumulate += rowscale*v
// GMODE 0: dense; 1: gather A rows via row_map (store compact); 2: scatter store via row_map
template<int ACT, int OMODE, int GMODE>
__global__ __launch_bounds__(256) void gemm_nt(
    const bf16* __restrict__ A, const bf16* __restrict__ B,
    const float* __restrict__ bias, const float* resid,
    const float* __restrict__ rowscale, int rs_stride,
    void* C, int M, int K, int O,
    const int* __restrict__ row_map, const int* __restrict__ cnt_ptr)
{
    const int bm = blockIdx.x, bn = blockIdx.y;
    int M_act = M;
    if (GMODE != 0) {
        M_act = *cnt_ptr;
        if (bm * 128 >= M_act) return;
    }
    __shared__ bf16 As[128][72];
    __shared__ bf16 Bs[128][72];
    const int t = threadIdx.x;
    const int lane = t & 63, wid = t >> 6;
    const int wm = wid >> 1, wn = wid & 1;
    f32x4 acc[4][4] = {};
    const int lr = t >> 3;
    const int lc = (t & 7) * 8;
    const size_t abase = (size_t)(bm * 128) * K;
    const size_t bbase = (size_t)(bn * 128) * K;
    int amap[4];
    if (GMODE == 1) {
        #pragma unroll
        for (int p = 0; p < 4; p++) {
            int gr = bm * 128 + p * 32 + lr;
            amap[p] = row_map[gr < M_act ? gr : M_act - 1];
        }
    }
    for (int k0 = 0; k0 < K; k0 += 64) {
        #pragma unroll
        for (int p = 0; p < 4; p++) {
            int r = p * 32 + lr;
            size_t arow = (GMODE == 1) ? (size_t)amap[p] * K : abase + (size_t)r * K;
            *(s8v*)&As[r][lc] = *(const s8v*)&A[arow + k0 + lc];
            *(s8v*)&Bs[r][lc] = *(const s8v*)&B[bbase + (size_t)r * K + k0 + lc];
        }
        __syncthreads();
        const int fr = lane & 15, fq = (lane >> 4) * 8;
        #pragma unroll
        for (int kk = 0; kk < 64; kk += 32) {
            s8v af[4], bfr[4];
            #pragma unroll
            for (int i = 0; i < 4; i++) {
                af[i]  = *(const s8v*)&As[wm * 64 + i * 16 + fr][kk + fq];
                bfr[i] = *(const s8v*)&Bs[wn * 64 + i * 16 + fr][kk + fq];
            }
            #pragma unroll
            for (int i = 0; i < 4; i++)
                #pragma unroll
                for (int j = 0; j < 4; j++)
                    acc[i][j] = __builtin_amdgcn_mfma_f32_16x16x32_bf16(af[i], bfr[j], acc[i][j], 0, 0, 0);
        }
        __syncthreads();
    }
    const int cr = lane & 15, quad = lane >> 4;
    #pragma unroll
    for (int i = 0; i < 4; i++) {
        #pragma unroll
        for (int r = 0; r < 4; r++) {
            int row = bm * 128 + wm * 64 + i * 16 + quad * 4 + r;
            if (GMODE != 0 && row >= M_act) continue;
            int srow = (GMODE == 2) ? row_map[row] : row;
            #pragma unroll
            for (int j = 0; j < 4; j++) {
                int col = bn * 128 + wn * 64 + j * 16 + cr;
                float v = acc[i][j][r];
                if (bias) v += bias[col];
                if (ACT == 1) v = 0.5f * v * (1.0f + erff(v * 0.70710678118f));
                size_t idx = (size_t)srow * O + col;
                if (OMODE == 0) {
                    float rv = resid ? resid[idx] : 0.0f;
                    ((float*)C)[idx] = rv + v;
                } else if (OMODE == 1) {
                    ((bf16*)C)[idx] = __float2bfloat16(v);
                } else {
                    ((float*)C)[idx] += rowscale[(size_t)srow * rs_stride] * v;
                }
            }
        }
    }
}

// ---------------- MFMA flash attention with ALiBi, fixed-shift softmax ----------------
// block: 256 thr = 4 waves, each wave owns 32 q-rows (128 q-rows/block)
__global__ __launch_bounds__(256) void attn_k(
    const bf16* __restrict__ Q, const bf16* __restrict__ K,
    const bf16* __restrict__ V, bf16* __restrict__ Y)
{
    __shared__ bf16 Ks[64][72];
    __shared__ bf16 Vt[64][66];
    __shared__ bf16 Pw[4][32][72];
    const int t = threadIdx.x;
    const int wave = t >> 6, lane = t & 63;
    const int qm = lane & 15, quad = lane >> 4;
    const int b = blockIdx.z, h = blockIdx.y;
    const int qbase = blockIdx.x * 128 + wave * 32;
    const float slope = exp2f(-0.5f * (float)(h + 1));

    s8v qa[2][2];
    #pragma unroll
    for (int g = 0; g < 2; g++) {
        const bf16* qp = Q + ((size_t)(b * SEQ + qbase + g * 16 + qm)) * D_MODEL + h * HD;
        qa[g][0] = *(const s8v*)&qp[quad * 8];
        qa[g][1] = *(const s8v*)&qp[32 + quad * 8];
    }

    f32x4 o[2][4] = {};
    float l[2][4] = {};

    const int sr = t >> 2;
    const int scc = (t & 3) * 16;

    for (int k0 = 0; k0 < SEQ; k0 += 64) {
        __syncthreads();
        const bf16* kp = K + ((size_t)(b * SEQ + k0 + sr)) * D_MODEL + h * HD + scc;
        const bf16* vp = V + ((size_t)(b * SEQ + k0 + sr)) * D_MODEL + h * HD + scc;
        s8v k0v = *(const s8v*)&kp[0];
        s8v k1v = *(const s8v*)&kp[8];
        s8v v0 = *(const s8v*)&vp[0];
        s8v v1 = *(const s8v*)&vp[8];
        *(s8v*)&Ks[sr][scc] = k0v;
        *(s8v*)&Ks[sr][scc + 8] = k1v;
        #pragma unroll
        for (int j = 0; j < 8; j++) {
            Vt[scc + j][sr]     = ((const bf16*)&v0)[j];
            Vt[scc + 8 + j][sr] = ((const bf16*)&v1)[j];
        }
        __syncthreads();
        #pragma unroll
        for (int g = 0; g < 2; g++) {
            f32x4 scr[4];
            #pragma unroll
            for (int jt = 0; jt < 4; jt++) {
                f32x4 z = {};
                s8v b0 = *(const s8v*)&Ks[jt * 16 + qm][quad * 8];
                s8v b1 = *(const s8v*)&Ks[jt * 16 + qm][32 + quad * 8];
                z = __builtin_amdgcn_mfma_f32_16x16x32_bf16(qa[g][0], b0, z, 0, 0, 0);
                z = __builtin_amdgcn_mfma_f32_16x16x32_bf16(qa[g][1], b1, z, 0, 0, 0);
                scr[jt] = z;
            }
            #pragma unroll
            for (int jt = 0; jt < 4; jt++) {
                int kcol = k0 + jt * 16 + qm;
                #pragma unroll
                for (int r = 0; r < 4; r++) {
                    int qrow = qbase + g * 16 + quad * 4 + r;
                    float dist = (float)max(kcol - qrow, 0);
                    float pf = __expf(fmaf(scr[jt][r], 0.125f, fmaf(-slope, dist, -8.0f)));
                    bf16 pb = __float2bfloat16(pf);
                    l[g][r] += __bfloat162float(pb);
                    Pw[wave][g * 16 + quad * 4 + r][jt * 16 + qm] = pb;
                }
            }
        }
        __builtin_amdgcn_wave_barrier();
        #pragma unroll
        for (int g = 0; g < 2; g++) {
            s8v pa0 = *(const s8v*)&Pw[wave][g * 16 + qm][quad * 8];
            s8v pa1 = *(const s8v*)&Pw[wave][g * 16 + qm][32 + quad * 8];
            #pragma unroll
            for (int dt = 0; dt < 4; dt++) {
                s8v vb0 = *(const s8v*)&Vt[dt * 16 + qm][quad * 8];
                s8v vb1 = *(const s8v*)&Vt[dt * 16 + qm][32 + quad * 8];
                o[g][dt] = __builtin_amdgcn_mfma_f32_16x16x32_bf16(pa0, vb0, o[g][dt], 0, 0, 0);
                o[g][dt] = __builtin_amdgcn_mfma_f32_16x16x32_bf16(pa1, vb1, o[g][dt], 0, 0, 0);
            }
        }
    }
    #pragma unroll
    for (int g = 0; g < 2; g++)
        #pragma unroll
        for (int r = 0; r < 4; r++) {
            float s = l[g][r];
            s += __shfl_xor(s, 1); s += __shfl_xor(s, 2);
            s += __shfl_xor(s, 4); s += __shfl_xor(s, 8);
            l[g][r] = 1.0f / s;
        }
    #pragma unroll
    for (int g = 0; g < 2; g++)
        #pragma unroll
        for (int dt = 0; dt < 4; dt++)
            #pragma unroll
            for (int r = 0; r < 4; r++) {
                size_t idx = ((size_t)(b * SEQ + qbase + g * 16 + quad * 4 + r)) * D_MODEL + h * HD + dt * 16 + qm;
                Y[idx] = __float2bfloat16(o[g][dt][r] * l[g][r]);
            }
}

// ---------------- router: gates, top-2 weights, aux, per-expert token lists ----------------
// grid 512 x 256thr; wave handles 4 tokens (block: 16 tokens)
__global__ __launch_bounds__(256) void router_k(
    const float* __restrict__ xf, const float* __restrict__ rw,
    float* __restrict__ wts, float* __restrict__ auxb,
    int* __restrict__ cnt, int* __restrict__ elist)
{
    const int wave = threadIdx.x >> 6, lane = threadIdx.x & 63;
    float4 w[4][4];
    #pragma unroll
    for (int e = 0; e < 4; e++)
        #pragma unroll
        for (int c = 0; c < 4; c++)
            w[e][c] = *(const float4*)&rw[e * D_MODEL + lane * 16 + c * 4];
    float ag[4] = {0.f, 0.f, 0.f, 0.f};
    float ac[4] = {0.f, 0.f, 0.f, 0.f};
    __shared__ int sel[16][2];
    __shared__ float sh[4][8];
    const int t0 = (blockIdx.x * 4 + wave) * 4;
    #pragma unroll
    for (int i = 0; i < 4; i++) {
        const int tk = t0 + i;
        const float* xr = xf + (size_t)tk * D_MODEL + lane * 16;
        float4 xv[4];
        #pragma unroll
        for (int c = 0; c < 4; c++) xv[c] = *(const float4*)&xr[c * 4];
        float p[4] = {0.f, 0.f, 0.f, 0.f};
        #pragma unroll
        for (int e = 0; e < 4; e++)
            #pragma unroll
            for (int c = 0; c < 4; c++) {
                p[e] = fmaf(xv[c].x, w[e][c].x, p[e]);
                p[e] = fmaf(xv[c].y, w[e][c].y, p[e]);
                p[e] = fmaf(xv[c].z, w[e][c].z, p[e]);
                p[e] = fmaf(xv[c].w, w[e][c].w, p[e]);
            }
        #pragma unroll
        for (int o = 1; o < 64; o <<= 1) {
            p[0] += __shfl_xor(p[0], o); p[1] += __shfl_xor(p[1], o);
            p[2] += __shfl_xor(p[2], o); p[3] += __shfl_xor(p[3], o);
        }
        float g[4];
        float mx = fmaxf(fmaxf(p[0], p[1]), fmaxf(p[2], p[3]));
        float se = 0.f;
        #pragma unroll
        for (int e = 0; e < 4; e++) { g[e] = __expf(p[e] - mx); se += g[e]; }
        #pragma unroll
        for (int e = 0; e < 4; e++) g[e] /= se;
        int i1 = 0; float v1 = g[0];
        #pragma unroll
        for (int e = 1; e < 4; e++) if (g[e] > v1) { v1 = g[e]; i1 = e; }
        int i2 = -1; float v2 = -1.f;
        #pragma unroll
        for (int e = 0; e < 4; e++) if (e != i1 && g[e] > v2) { v2 = g[e]; i2 = e; }
        float sw = fmaxf(v1 + v2, 1e-9f);
        if (lane < 4) {
            float wv = (lane == i1) ? v1 / sw : ((lane == i2) ? v2 / sw : 0.f);
            wts[(size_t)tk * 4 + lane] = wv;
        }
        if (lane == 0) {
            #pragma unroll
            for (int e = 0; e < 4; e++) ag[e] += g[e];
            ac[i1] += 1.f; ac[i2] += 1.f;
            sel[wave * 4 + i][0] = i1;
            sel[wave * 4 + i][1] = i2;
        }
    }
    if (lane == 0)
        #pragma unroll
        for (int e = 0; e < 4; e++) { sh[wave][e] = ag[e]; sh[wave][4 + e] = ac[e]; }
    __syncthreads();
    if (threadIdx.x < 8) {
        float s = sh[0][threadIdx.x] + sh[1][threadIdx.x] + sh[2][threadIdx.x] + sh[3][threadIdx.x];
        atomicAdd(&auxb[threadIdx.x], s);
    }
    if (threadIdx.x < 4) {
        const int e = threadIdx.x;
        int loc[16]; int c = 0;
        #pragma unroll
        for (int s = 0; s < 16; s++)
            if (sel[s][0] == e || sel[s][1] == e) loc[c++] = blockIdx.x * 16 + s;
        if (c) {
            int base = atomicAdd(&cnt[e], c);
            for (int k = 0; k < c; k++) elist[e * TOKENS + base + k] = loc[k];
        }
    }
}

// ---------------- final: out = x_s + depthwise-conv5(Tr) + tb ----------------
__global__ __launch_bounds__(256) void final_k(
    const float* __restrict__ xs, const float* __restrict__ Tr,
    const float* __restrict__ tw, const float* __restrict__ tb, float* __restrict__ out)
{
    int n = blockIdx.x, b = blockIdx.y, t = threadIdx.x;
    for (int d = t; d < D_MODEL; d += 256) {
        float acc = tb[d];
        #pragma unroll
        for (int j = 0; j < 5; j++) {
            int i = n + j - 2;
            if (i >= 0 && i < SEQ)
                acc += Tr[((size_t)(b * SEQ + i)) * D_MODEL + d] * tw[d * 5 + j];
        }
        size_t idx = ((size_t)(b * SEQ + n)) * D_MODEL + d;
        out[idx] = xs[idx] + acc;
    }
}

__global__ void aux_k(const float* __restrict__ ab, float* __restrict__ out) {
    if (threadIdx.x == 0 && blockIdx.x == 0) {
        float a = 0.f;
        for (int e = 0; e < 4; e++)
            a += (ab[e] / (float)TOKENS) * (ab[4 + e] / (float)TOKENS);
        out[0] = 4.0f * a;
    }
}

extern "C" void kernel_launch(void* const* d_in, const int* in_sizes, int n_in,
                              void* d_out, int out_size, void* d_ws, size_t ws_size,
                              hipStream_t stream)
{
    const float* x    = (const float*)d_in[0];
    const float* qw   = (const float*)d_in[1];
    const float* qb   = (const float*)d_in[2];
    const float* kw   = (const float*)d_in[3];
    const float* kb   = (const float*)d_in[4];
    const float* vw   = (const float*)d_in[5];
    const float* vb   = (const float*)d_in[6];
    const float* ow   = (const float*)d_in[7];
    const float* ob   = (const float*)d_in[8];
    const float* n1g  = (const float*)d_in[9];
    const float* n1b  = (const float*)d_in[10];
    const float* n2g  = (const float*)d_in[11];
    const float* n2b  = (const float*)d_in[12];
    const float* alpha= (const float*)d_in[13];
    const float* dw7  = (const float*)d_in[14];
    const float* dw25 = (const float*)d_in[15];
    const float* dw49 = (const float*)d_in[16];
    const float* rw   = (const float*)d_in[17];
    const float* ew1  = (const float*)d_in[18];
    const float* eb1  = (const float*)d_in[19];
    const float* ew2  = (const float*)d_in[20];
    const float* eb2  = (const float*)d_in[21];
    const float* tw   = (const float*)d_in[22];
    const float* tb   = (const float*)d_in[23];

    char* ws = (char*)d_ws;
    const size_t MBy = 1ull << 20;
    float* S    = (float*)(ws + 0 * MBy);
    float* Tr   = (float*)(ws + 32 * MBy);
    float* XF   = (float*)(ws + 64 * MBy);
    bf16*  SNB  = (bf16*)(ws + 96 * MBy);
    bf16*  QB   = (bf16*)(ws + 112 * MBy);
    bf16*  KB   = (bf16*)(ws + 128 * MBy);
    bf16*  VB   = (bf16*)(ws + 144 * MBy);
    bf16*  XFB  = (bf16*)(ws + 160 * MBy);
    bf16*  WQ   = (bf16*)(ws + 176 * MBy);
    bf16*  WK   = (bf16*)(ws + 178 * MBy);
    bf16*  WV   = (bf16*)(ws + 180 * MBy);
    bf16*  WO   = (bf16*)(ws + 182 * MBy);
    bf16*  WE1  = (bf16*)(ws + 184 * MBy);
    bf16*  WE2  = (bf16*)(ws + 200 * MBy);
    float* WTS  = (float*)(ws + 216 * MBy);
    float* AUXB = (float*)(ws + 217 * MBy);   // 8 floats
    int*   CNT  = (int*)(AUXB + 8);           // 4 ints
    int*   ELST = (int*)(ws + 218 * MBy);     // 4 * 8192 ints
    bf16*  YB = SNB;
    bf16*  HB = QB;   // [8192,2048] spans QB+KB

    f2b_k<<<2048, 256, 0, stream>>>(qw, WQ, D_MODEL * D_MODEL);
    f2b_k<<<2048, 256, 0, stream>>>(kw, WK, D_MODEL * D_MODEL);
    f2b_k<<<2048, 256, 0, stream>>>(vw, WV, D_MODEL * D_MODEL);
    f2b_k<<<2048, 256, 0, stream>>>(ow, WO, D_MODEL * D_MODEL);
    f2b_k<<<4096, 256, 0, stream>>>(ew1, WE1, 4 * MOE_H * D_MODEL);
    f2b_k<<<4096, 256, 0, stream>>>(ew2, WE2, 4 * D_MODEL * MOE_H);

    decomp_k<<<dim3(SEQ / TN, D_MODEL / TD, NB), 256, 0, stream>>>(x, alpha, dw7, dw25, dw49, Tr, S);

    ln_k<<<TOKENS, 256, 0, stream>>>(S, n1g, n1b, SNB, nullptr);

    gemm_nt<0, 1, 0><<<dim3(64, 8), 256, 0, stream>>>(SNB, WQ, qb, nullptr, nullptr, 0, QB, TOKENS, D_MODEL, D_MODEL, nullptr, nullptr);
    gemm_nt<0, 1, 0><<<dim3(64, 8), 256, 0, stream>>>(SNB, WK, kb, nullptr, nullptr, 0, KB, TOKENS, D_MODEL, D_MODEL, nullptr, nullptr);
    gemm_nt<0, 1, 0><<<dim3(64, 8), 256, 0, stream>>>(SNB, WV, vb, nullptr, nullptr, 0, VB, TOKENS, D_MODEL, D_MODEL, nullptr, nullptr);

    attn_k<<<dim3(SEQ / 128, NHEAD, NB), 256, 0, stream>>>(QB, KB, VB, YB);

    gemm_nt<0, 0, 0><<<dim3(64, 8), 256, 0, stream>>>(YB, WO, ob, S, nullptr, 0, S, TOKENS, D_MODEL, D_MODEL, nullptr, nullptr);

    ln_k<<<TOKENS, 256, 0, stream>>>(S, n2g, n2b, XFB, XF);

    hipMemsetAsync(AUXB, 0, 64, stream);
    router_k<<<TOKENS / 16, 256, 0, stream>>>(XF, rw, WTS, AUXB, CNT, ELST);

    // sparse top-2 MoE: only routed tokens, gathered per expert
    for (int e = 0; e < 4; e++) {
        gemm_nt<1, 1, 1><<<dim3(64, 16), 256, 0, stream>>>(
            XFB, WE1 + (size_t)e * MOE_H * D_MODEL, eb1 + e * MOE_H,
            nullptr, nullptr, 0, HB, TOKENS, D_MODEL, MOE_H,
            ELST + e * TOKENS, CNT + e);
        gemm_nt<0, 2, 2><<<dim3(64, 8), 256, 0, stream>>>(
            HB, WE2 + (size_t)e * D_MODEL * MOE_H, eb2 + e * D_MODEL,
            nullptr, WTS + e, 4, S, TOKENS, MOE_H, D_MODEL,
            ELST + e * TOKENS, CNT + e);
    }

    final_k<<<dim3(SEQ, NB), 256, 0, stream>>>(S, Tr, tw, tb, (float*)d_out);
    aux_k<<<1, 64, 0, stream>>>(AUXB, (float*)d_out + (out_size - 1));
}